// Round 2
// baseline (476.153 us; speedup 1.0000x reference)
//
#include <hip/hip_runtime.h>

#define NN 50000
#define EE 600000
#define BB 64
#define CH 128
#define LL 3
#define TR 64     // rows per GEMM tile
#define NGB 782   // ceil(50000/64)
#define NSB 196   // scan blocks = ceil(50000/256)
#define NPB 392   // pool blocks = ceil(50000/128)

typedef unsigned short u16;
typedef unsigned int u32;
typedef short s16x8 __attribute__((ext_vector_type(8)));
typedef float f32x4 __attribute__((ext_vector_type(4)));

__device__ __forceinline__ u16 f2b(float f) {
    u32 x = __float_as_uint(f);
    return (u16)((x + 0x7FFFu + ((x >> 16) & 1u)) >> 16);  // RNE f32->bf16
}
__device__ __forceinline__ float b2f(u16 u) {
    return __uint_as_float(((u32)u) << 16);
}

// ---------------------------------------------------------------------------
// k_prep: fused zero (deg/pooled/gstats) + x->bf16 cvt + weight transpose.
// grid 3125 x 256. All three tasks independent; range-dispatch by blockIdx.
// slots 0-2: convW1[l], 3-5: convW2[l], 6: recW1, 7: recW2, 8: recW3 (zero-pad)
// ---------------------------------------------------------------------------
__global__ __launch_bounds__(256) void k_prep(
    const float* __restrict__ x, u16* __restrict__ x16,
    const float* __restrict__ cW1, const float* __restrict__ cW2,
    const float* __restrict__ rW1, const float* __restrict__ rW2,
    const float* __restrict__ rW3, u16* __restrict__ Wt,
    int* __restrict__ deg, float* __restrict__ pooled,
    float* __restrict__ gstats) {
    int gid = blockIdx.x * 256 + threadIdx.x;

    // task 1: cvt (all 3125 blocks)
    long base = (long)gid * 8;
    if (base < (long)NN * CH) {
        float4 f0 = *(const float4*)(x + base);
        float4 f1 = *(const float4*)(x + base + 4);
        union { u16 pk[8]; uint4 v; } uu;
        uu.pk[0] = f2b(f0.x); uu.pk[1] = f2b(f0.y);
        uu.pk[2] = f2b(f0.z); uu.pk[3] = f2b(f0.w);
        uu.pk[4] = f2b(f1.x); uu.pk[5] = f2b(f1.y);
        uu.pk[6] = f2b(f1.z); uu.pk[7] = f2b(f1.w);
        *(uint4*)(x16 + base) = uu.v;
    }
    // task 2: weight transpose (blocks 0..575)
    if (gid < 8 * 16384) {
        int slot = gid >> 14;
        int wi = gid & 16383;
        int k = wi >> 7, n = wi & 127;
        const float* src = slot < 3 ? cW1 + slot * 16384
                         : slot < 6 ? cW2 + (slot - 3) * 16384
                         : slot == 6 ? rW1 : rW2;
        Wt[slot * 16384 + n * 128 + k] = f2b(src[wi]);
    } else if (gid < 9 * 16384) {
        int j = gid - 8 * 16384;
        int n = j >> 7, k = j & 127;
        Wt[8 * 16384 + j] = (n < 4) ? f2b(rW3[k * 4 + n]) : (u16)0;
    }
    // task 3: zeroing (blocks 0..230)
    if (gid < NN) deg[gid] = 0;
    int j2 = gid - NN;
    if (j2 >= 0 && j2 < BB * CH) pooled[j2] = 0.f;
    int k2 = j2 - BB * CH;
    if (k2 >= 0 && k2 < 3 * 256) gstats[k2] = 0.f;
}

__global__ __launch_bounds__(256) void k_count(const int* __restrict__ ei,
                                               int* __restrict__ deg) {
    int e = blockIdx.x * 256 + threadIdx.x;
    if (e < EE) atomicAdd(&deg[ei[EE + e]], 1);
}

// stage A: per-block (256 elems) sum of deg -> bsum[blk]
__global__ __launch_bounds__(256) void k_scanA(const int* __restrict__ deg,
                                               int* __restrict__ bsum) {
    __shared__ int sm[256];
    int i = blockIdx.x * 256 + threadIdx.x;
    sm[threadIdx.x] = (i < NN) ? deg[i] : 0;
    __syncthreads();
    for (int off = 128; off > 0; off >>= 1) {
        if (threadIdx.x < off) sm[threadIdx.x] += sm[threadIdx.x + off];
        __syncthreads();
    }
    if (threadIdx.x == 0) bsum[blockIdx.x] = sm[0];
}

// stage B: scan bsum in LDS -> block offset; local scan -> rowptr & cur
__global__ __launch_bounds__(256) void k_scanB(const int* __restrict__ deg,
                                               const int* __restrict__ bsum,
                                               int* __restrict__ rowptr,
                                               int* __restrict__ cur) {
    __shared__ int sb[256], sd[256];
    int t = threadIdx.x;
    sb[t] = (t < NSB) ? bsum[t] : 0;
    __syncthreads();
    for (int off = 1; off < 256; off <<= 1) {
        int v = (t >= off) ? sb[t - off] : 0;
        __syncthreads();
        sb[t] += v;
        __syncthreads();
    }
    int blockOff = (blockIdx.x == 0) ? 0 : sb[blockIdx.x - 1];
    int i = blockIdx.x * 256 + t;
    int d = (i < NN) ? deg[i] : 0;
    sd[t] = d;
    __syncthreads();
    for (int off = 1; off < 256; off <<= 1) {
        int v = (t >= off) ? sd[t - off] : 0;
        __syncthreads();
        sd[t] += v;
        __syncthreads();
    }
    int excl = blockOff + sd[t] - d;
    if (i < NN) { rowptr[i] = excl; cur[i] = excl; }
    if (i == NN - 1) rowptr[NN] = excl + d;
}

__global__ __launch_bounds__(256) void k_fill(const int* __restrict__ ei,
                                              int* __restrict__ cur,
                                              int* __restrict__ perm) {
    int e = blockIdx.x * 256 + threadIdx.x;
    if (e < EE) {
        int dst = ei[EE + e];
        int idx = atomicAdd(&cur[dst], 1);
        perm[idx] = ei[e];
    }
}

// ---------------------------------------------------------------------------
// Shared GEMM building blocks (layouts verified m89/m91; XOR-swizzle c^(r&15))
// ---------------------------------------------------------------------------
__device__ __forceinline__ void stageB8(const u16* __restrict__ Wt, u16* sB,
                                        int s, int rr) {
#pragma unroll
    for (int it = 0; it < 8; ++it) {
        int n = it * 16 + rr;
        uint4 u = *(const uint4*)(Wt + n * CH + 8 * s);
        *(uint4*)(&sB[n * CH + ((s ^ (n & 15)) * 8)]) = u;
    }
}

template <int M>
__device__ __forceinline__ void mfmaT(const u16* sA, const u16* sB,
                                      f32x4 (&acc)[M][8], int rowbase, int quad,
                                      int l16) {
    f32x4 z = {0.f, 0.f, 0.f, 0.f};
#pragma unroll
    for (int m = 0; m < M; ++m)
#pragma unroll
        for (int t = 0; t < 8; ++t) acc[m][t] = z;
#pragma unroll
    for (int kc = 0; kc < 4; ++kc) {
        int off = (((kc << 2) | quad) ^ l16) << 3;
        s16x8 a[M];
#pragma unroll
        for (int m = 0; m < M; ++m)
            a[m] = *(const s16x8*)(sA + (rowbase + m * 16 + l16) * CH + off);
#pragma unroll
        for (int t = 0; t < 8; ++t) {
            s16x8 bfr = *(const s16x8*)(sB + (t * 16 + l16) * CH + off);
#pragma unroll
            for (int m = 0; m < M; ++m)
                acc[m][t] = __builtin_amdgcn_mfma_f32_16x16x32_bf16(a[m], bfr, acc[m][t], 0, 0, 0);
        }
    }
}

template <int M>
__device__ __forceinline__ void biasreluT(f32x4 (&acc)[M][8],
                                          const float* __restrict__ bias, int l16) {
#pragma unroll
    for (int t = 0; t < 8; ++t) {
        float bv = bias[t * 16 + l16];
#pragma unroll
        for (int m = 0; m < M; ++m)
#pragma unroll
            for (int r = 0; r < 4; ++r)
                acc[m][t][r] = fmaxf(acc[m][t][r] + bv, 0.f);
    }
}

// write C tile (in acc) back into sA as bf16 with the A-read XOR-swizzle.
template <int M>
__device__ __forceinline__ void restageT(const f32x4 (&acc)[M][8], u16* sA,
                                         int rowbase, int quad, int l16) {
#pragma unroll
    for (int t = 0; t < 8; ++t) {
        int chunk = (t << 1) | (l16 >> 3);
        int o7 = l16 & 7;
#pragma unroll
        for (int m = 0; m < M; ++m)
#pragma unroll
            for (int r = 0; r < 4; ++r) {
                int lr = rowbase + m * 16 + quad * 4 + r;
                sA[lr * CH + ((chunk ^ (lr & 15)) << 3) + o7] = f2b(acc[m][t][r]);
            }
    }
}

// ---------------------------------------------------------------------------
// k_gg1: fused gather + GEMM1 + BN stats.
//   Each block owns rows [r0, r0+64). 16-lane groups gather 4 rows each
//   (agg = x[dst] + sum x[src]) straight into the swizzled LDS A-tile —
//   no global y16 round trip. Then h = A@W1 + b1 (kept in regs),
//   stat partials -> atomicAdd gstats, h -> h16 (bf16).
// ---------------------------------------------------------------------------
__global__ __launch_bounds__(256, 3) void k_gg1(
    const u16* __restrict__ x, const int* __restrict__ rowptr,
    const int* __restrict__ perm, const u16* __restrict__ Wt, int layer,
    const float* __restrict__ cb1, float* __restrict__ gstats,
    u16* __restrict__ h16) {
    __shared__ u16 sA[TR * CH];
    __shared__ u16 sB[128 * CH];
    const int tid = threadIdx.x;
    const int s = tid & 15, rr = tid >> 4;
    const int r0 = blockIdx.x * TR;
    const int lane = tid & 63, wv = tid >> 6, quad = lane >> 4, l16 = lane & 15;

    stageB8(Wt + layer * 16384, sB, s, rr);

    // ---- gather 4 rows per 16-lane group, write swizzled into sA ----
    {
        int co = s * 8;
#pragma unroll
        for (int rl = rr; rl < TR; rl += 16) {
            int dst = r0 + rl;
            float a[8], b[8];
#pragma unroll
            for (int j = 0; j < 8; ++j) { a[j] = 0.f; b[j] = 0.f; }
            if (dst < NN) {
                union { u16 pk[8]; uint4 v; } uu;
                uu.v = *(const uint4*)(x + (long)dst * CH + co);
#pragma unroll
                for (int j = 0; j < 8; ++j) a[j] = b2f(uu.pk[j]);
                int beg = rowptr[dst], end = rowptr[dst + 1];
                int e = beg;
                for (; e + 1 < end; e += 2) {
                    int s0 = perm[e], s1 = perm[e + 1];
                    union { u16 pk[8]; uint4 v; } v0, v1;
                    v0.v = *(const uint4*)(x + (long)s0 * CH + co);
                    v1.v = *(const uint4*)(x + (long)s1 * CH + co);
#pragma unroll
                    for (int j = 0; j < 8; ++j) { a[j] += b2f(v0.pk[j]); b[j] += b2f(v1.pk[j]); }
                }
                if (e < end) {
                    int s0 = perm[e];
                    union { u16 pk[8]; uint4 v; } v0;
                    v0.v = *(const uint4*)(x + (long)s0 * CH + co);
#pragma unroll
                    for (int j = 0; j < 8; ++j) a[j] += b2f(v0.pk[j]);
                }
            }
            union { u16 pk[8]; uint4 v; } ov;
#pragma unroll
            for (int j = 0; j < 8; ++j) ov.pk[j] = f2b(a[j] + b[j]);
            *(uint4*)(&sA[rl * CH + ((s ^ (rl & 15)) * 8)]) = ov.v;
        }
    }
    __syncthreads();

    f32x4 acc[1][8];
    mfmaT<1>(sA, sB, acc, wv * 16, quad, l16);

    // bias add (h pre-relu kept in acc) + stats over valid rows
    float ss[8], qq[8];
#pragma unroll
    for (int t = 0; t < 8; ++t) {
        float bv = cb1[t * 16 + l16];
        ss[t] = 0.f; qq[t] = 0.f;
        int rbase = r0 + wv * 16 + quad * 4;
#pragma unroll
        for (int r = 0; r < 4; ++r) {
            float v = acc[0][t][r] + bv;
            acc[0][t][r] = v;
            if (rbase + r < NN) { ss[t] += v; qq[t] += v * v; }
        }
    }
#pragma unroll
    for (int t = 0; t < 8; ++t) {
        ss[t] += __shfl_xor(ss[t], 16);
        ss[t] += __shfl_xor(ss[t], 32);
        qq[t] += __shfl_xor(qq[t], 16);
        qq[t] += __shfl_xor(qq[t], 32);
    }

    // write h (pre-BN, bf16) to h16 — global stores fly while we reduce
#pragma unroll
    for (int t = 0; t < 8; ++t) {
        int col = t * 16 + l16;
#pragma unroll
        for (int r = 0; r < 4; ++r) {
            int row = r0 + wv * 16 + quad * 4 + r;
            if (row < NN) h16[(long)row * CH + col] = f2b(acc[0][t][r]);
        }
    }

    float* red = (float*)sA;
    __syncthreads();  // all waves done reading sA in mfmaT
    if (lane < 16) {
#pragma unroll
        for (int t = 0; t < 8; ++t) {
            red[wv * 256 + t * 16 + l16] = ss[t];
            red[wv * 256 + 128 + t * 16 + l16] = qq[t];
        }
    }
    __syncthreads();
    unsafeAtomicAdd(&gstats[tid],
                    red[tid] + red[256 + tid] + red[512 + tid] + red[768 + tid]);
}

// ---------------------------------------------------------------------------
// k_gemm2: sc/sh from gstats (plain loads — kernel-boundary coherence);
// BN+ReLU folded into the A-stage bf16 conversion; GEMM2 -> xc.
// LAST: tile-resident rec1/rec2/rec3 -> x_rec.
// ---------------------------------------------------------------------------
template <bool LAST>
__global__ __launch_bounds__(256, 3) void k_gemm2(
    const u16* __restrict__ h16, const u16* __restrict__ Wt, int layer,
    const float* __restrict__ g, const float* __restrict__ bbeta,
    const float* __restrict__ gstats, const float* __restrict__ cb2,
    u16* __restrict__ xc,
    const float* __restrict__ rb1, const float* __restrict__ rb2,
    const float* __restrict__ rb3, float* __restrict__ x_rec) {
    __shared__ u16 sA[TR * CH];
    __shared__ u16 sB[128 * CH];
    __shared__ float snorm[256];  // sc[128], sh[128]
    const int tid = threadIdx.x;
    const int s = tid & 15, rr = tid >> 4;
    const int r0 = blockIdx.x * TR;
    const int lane = tid & 63, wv = tid >> 6, quad = lane >> 4, l16 = lane & 15;

    if (tid < 128) {
        float sum = gstats[tid];
        float sq = gstats[128 + tid];
        float mu = sum / (float)NN;
        float var = sq / (float)NN - mu * mu;
        float sc = g[tid] * rsqrtf(var + 1e-5f);
        snorm[tid] = sc;
        snorm[128 + tid] = bbeta[tid] - mu * sc;
    }
    stageB8(Wt + (3 + layer) * 16384, sB, s, rr);
    __syncthreads();  // snorm ready

#pragma unroll
    for (int it = 0; it < 4; ++it) {
        int lr = it * 16 + rr, gr = r0 + lr;
        union { u16 pk[8]; uint4 v; } uu;
        if (gr < NN) {
            uu.v = *(const uint4*)(h16 + (long)gr * CH + 8 * s);
#pragma unroll
            for (int j = 0; j < 8; ++j) {
                int c = 8 * s + j;
                float v = fmaxf(b2f(uu.pk[j]) * snorm[c] + snorm[128 + c], 0.f);
                uu.pk[j] = f2b(v);
            }
        } else {
#pragma unroll
            for (int j = 0; j < 8; ++j) uu.pk[j] = 0;
        }
        *(uint4*)(&sA[lr * CH + ((s ^ (lr & 15)) * 8)]) = uu.v;
    }
    __syncthreads();
    f32x4 acc[1][8];
    mfmaT<1>(sA, sB, acc, wv * 16, quad, l16);
    biasreluT<1>(acc, cb2, l16);
#pragma unroll
    for (int t = 0; t < 8; ++t) {
        int col = t * 16 + l16;
#pragma unroll
        for (int r = 0; r < 4; ++r) {
            int row = r0 + wv * 16 + quad * 4 + r;
            if (row < NN) xc[(long)row * CH + col] = f2b(acc[0][t][r]);
        }
    }

    if constexpr (LAST) {
        // ---- rec1 ----
        __syncthreads();
        restageT<1>(acc, sA, wv * 16, quad, l16);
        stageB8(Wt + 6 * 16384, sB, s, rr);
        __syncthreads();
        mfmaT<1>(sA, sB, acc, wv * 16, quad, l16);
        biasreluT<1>(acc, rb1, l16);
        // ---- rec2 ----
        __syncthreads();
        restageT<1>(acc, sA, wv * 16, quad, l16);
        stageB8(Wt + 7 * 16384, sB, s, rr);
        __syncthreads();
        mfmaT<1>(sA, sB, acc, wv * 16, quad, l16);
        biasreluT<1>(acc, rb2, l16);
        // ---- rec3 (N=4, one 16-col tile) ----
        __syncthreads();
        restageT<1>(acc, sA, wv * 16, quad, l16);
        {
            int n = rr;  // 16 B-rows
            uint4 u = *(const uint4*)(Wt + 8 * 16384 + n * CH + 8 * s);
            *(uint4*)(&sB[n * CH + ((s ^ (n & 15)) * 8)]) = u;
        }
        __syncthreads();
        f32x4 a4 = {0.f, 0.f, 0.f, 0.f};
        const u16* pa0 = sA + (wv * 16 + l16) * CH;
#pragma unroll
        for (int kc = 0; kc < 4; ++kc) {
            int off = (((kc << 2) | quad) ^ l16) << 3;
            s16x8 a0 = *(const s16x8*)(pa0 + off);
            s16x8 bfr = *(const s16x8*)(sB + l16 * CH + off);
            a4 = __builtin_amdgcn_mfma_f32_16x16x32_bf16(a0, bfr, a4, 0, 0, 0);
        }
        if (l16 < 4) {
            float bv = rb3[l16];
#pragma unroll
            for (int r = 0; r < 4; ++r) {
                int row = r0 + wv * 16 + quad * 4 + r;
                if (row < NN) x_rec[(long)row * 4 + l16] = fmaxf(a4[r] + bv, 0.f);
            }
        }
    }
}

// ---------------------------------------------------------------------------
// global_add_pool, parallel: 392 blocks x 128 rows; run-length accumulate.
// ---------------------------------------------------------------------------
__global__ __launch_bounds__(256) void k_pool(const u16* __restrict__ x,
                                              const int* __restrict__ batch,
                                              float* __restrict__ pooled) {
    int r0 = blockIdx.x * 128;
    if (r0 >= NN) return;
    int rend = r0 + 128 < NN ? r0 + 128 : NN;
    int c = threadIdx.x & 127;
    int half = threadIdx.x >> 7;
    int r = r0 + half;
    if (r >= rend) return;
    int g = batch[r];
    float s = 0.f;
    for (; r < rend; r += 2) {
        int gg = batch[r];
        if (gg != g) {
            unsafeAtomicAdd(pooled + g * CH + c, s);
            s = 0.f;
            g = gg;
        }
        s += b2f(x[(long)r * CH + c]);
    }
    unsafeAtomicAdd(pooled + g * CH + c, s);
}

// out[b] = relu(pooled[b] @ W1 + b1) @ W2 + b2  ; grid 64 x 128, all f32
__global__ __launch_bounds__(128) void k_mlp(const float* __restrict__ pooled,
                                             const float* __restrict__ W1,
                                             const float* __restrict__ b1,
                                             const float* __restrict__ W2,
                                             const float* __restrict__ b2,
                                             float* __restrict__ out) {
    __shared__ float p[128], t1[128];
    int b = blockIdx.x, t = threadIdx.x;
    p[t] = pooled[b * CH + t];
    __syncthreads();
    float acc = b1[t];
    for (int k = 0; k < 128; ++k) acc += p[k] * W1[k * 128 + t];
    t1[t] = fmaxf(acc, 0.f);
    __syncthreads();
    if (t < 64) {
        float o = b2[t];
        for (int k = 0; k < 128; ++k) o += t1[k] * W2[k * 64 + t];
        out[b * 64 + t] = o;
    }
}

// ---------------------------------------------------------------------------
extern "C" void kernel_launch(void* const* d_in, const int* in_sizes, int n_in,
                              void* d_out, int out_size, void* d_ws, size_t ws_size,
                              hipStream_t stream) {
    const float* x_in   = (const float*)d_in[0];
    const int*   ei     = (const int*)d_in[1];
    const int*   batch  = (const int*)d_in[2];
    const float* convW1 = (const float*)d_in[3];
    const float* convb1 = (const float*)d_in[4];
    const float* bn_g   = (const float*)d_in[5];
    const float* bn_b   = (const float*)d_in[6];
    const float* convW2 = (const float*)d_in[7];
    const float* convb2 = (const float*)d_in[8];
    const float* recW1  = (const float*)d_in[9];
    const float* recb1  = (const float*)d_in[10];
    const float* recW2  = (const float*)d_in[11];
    const float* recb2  = (const float*)d_in[12];
    const float* recW3  = (const float*)d_in[13];
    const float* recb3  = (const float*)d_in[14];
    const float* mlpW1  = (const float*)d_in[15];
    const float* mlpb1  = (const float*)d_in[16];
    const float* mlpW2  = (const float*)d_in[17];
    const float* mlpb2  = (const float*)d_in[18];

    float* out   = (float*)d_out;      // [64*64] out, then [50000*4] x_rec
    float* x_rec = out + 4096;

    char* w = (char*)d_ws;
    u16*   x16    = (u16*)w;    w += (size_t)NN * CH * 2;      // bf16 copy of x_in
    u16*   h16    = (u16*)w;    w += (size_t)NN * CH * 2;      // GEMM1 output (pre-BN)
    u16*   xc     = (u16*)w;    w += (size_t)NN * CH * 2;      // layer output
    u16*   Wt     = (u16*)w;    w += (size_t)9 * 16384 * 2;    // transposed bf16 weights
    float* gstats = (float*)w;  w += (size_t)3 * 256 * 4;      // BN sums per layer
    float* pooled = (float*)w;  w += (size_t)BB * CH * 4;
    int*   deg    = (int*)w;    w += (size_t)NN * 4;
    int*   bsum   = (int*)w;    w += (size_t)NSB * 4;
    int*   rowptr = (int*)w;    w += (size_t)(NN + 1) * 4;
    int*   cur    = (int*)w;    w += (size_t)NN * 4;
    int*   perm   = (int*)w;    w += (size_t)EE * 4;

    dim3 b256(256), b128(128);

    // prep (zero + cvt + transpose) then CSR build
    k_prep<<<3125, b256, 0, stream>>>(x_in, x16, convW1, convW2, recW1, recW2,
                                      recW3, Wt, deg, pooled, gstats);
    k_count<<<2344, b256, 0, stream>>>(ei, deg);
    k_scanA<<<NSB, b256, 0, stream>>>(deg, bsum);
    k_scanB<<<NSB, b256, 0, stream>>>(deg, bsum, rowptr, cur);
    k_fill<<<2344, b256, 0, stream>>>(ei, cur, perm);

    const u16* cur_x = x16;
    for (int l = 0; l < LL; ++l) {
        k_gg1<<<NGB, b256, 0, stream>>>(cur_x, rowptr, perm, Wt, l,
                                        convb1 + l * 128, gstats + l * 256, h16);
        if (l < LL - 1)
            k_gemm2<false><<<NGB, b256, 0, stream>>>(
                h16, Wt, l, bn_g + l * 128, bn_b + l * 128, gstats + l * 256,
                convb2 + l * 128, xc, recb1, recb2, recb3, x_rec);
        else
            k_gemm2<true><<<NGB, b256, 0, stream>>>(
                h16, Wt, l, bn_g + l * 128, bn_b + l * 128, gstats + l * 256,
                convb2 + l * 128, xc, recb1, recb2, recb3, x_rec);
        cur_x = xc;
    }
    // pooling + final MLP
    k_pool<<<NPB, b256, 0, stream>>>(xc, batch, pooled);
    k_mlp<<<64, b128, 0, stream>>>(pooled, mlpW1, mlpb1, mlpW2, mlpb2, out);
}

// Round 3
// 424.226 us; speedup vs baseline: 1.1224x; 1.1224x over previous
//
#include <hip/hip_runtime.h>

#define NN 50000
#define EE 600000
#define BB 64
#define CH 128
#define LL 3
#define TR 64     // rows per GEMM tile
#define NGB 782   // ceil(50000/64)
#define NGA 12500 // gather blocks = 50000/4 (one dst per wave)
#define NSB 196   // scan blocks = ceil(50000/256)
#define NPB 392   // pool blocks = ceil(50000/128)

typedef unsigned short u16;
typedef unsigned int u32;
typedef short s16x8 __attribute__((ext_vector_type(8)));
typedef float f32x4 __attribute__((ext_vector_type(4)));

__device__ __forceinline__ u16 f2b(float f) {
    u32 x = __float_as_uint(f);
    return (u16)((x + 0x7FFFu + ((x >> 16) & 1u)) >> 16);  // RNE f32->bf16
}
__device__ __forceinline__ float b2f(u16 u) {
    return __uint_as_float(((u32)u) << 16);
}

// ---------------------------------------------------------------------------
// k_prep: fused zero (deg/pooled/gstats) + x->bf16 cvt + weight transpose.
// grid 3125 x 256. All three tasks independent; range-dispatch by blockIdx.
// slots 0-2: convW1[l], 3-5: convW2[l], 6: recW1, 7: recW2, 8: recW3 (zero-pad)
// ---------------------------------------------------------------------------
__global__ __launch_bounds__(256) void k_prep(
    const float* __restrict__ x, u16* __restrict__ x16,
    const float* __restrict__ cW1, const float* __restrict__ cW2,
    const float* __restrict__ rW1, const float* __restrict__ rW2,
    const float* __restrict__ rW3, u16* __restrict__ Wt,
    int* __restrict__ deg, float* __restrict__ pooled,
    float* __restrict__ gstats) {
    int gid = blockIdx.x * 256 + threadIdx.x;

    // task 1: cvt (all 3125 blocks)
    long base = (long)gid * 8;
    if (base < (long)NN * CH) {
        float4 f0 = *(const float4*)(x + base);
        float4 f1 = *(const float4*)(x + base + 4);
        union { u16 pk[8]; uint4 v; } uu;
        uu.pk[0] = f2b(f0.x); uu.pk[1] = f2b(f0.y);
        uu.pk[2] = f2b(f0.z); uu.pk[3] = f2b(f0.w);
        uu.pk[4] = f2b(f1.x); uu.pk[5] = f2b(f1.y);
        uu.pk[6] = f2b(f1.z); uu.pk[7] = f2b(f1.w);
        *(uint4*)(x16 + base) = uu.v;
    }
    // task 2: weight transpose (blocks 0..575)
    if (gid < 8 * 16384) {
        int slot = gid >> 14;
        int wi = gid & 16383;
        int k = wi >> 7, n = wi & 127;
        const float* src = slot < 3 ? cW1 + slot * 16384
                         : slot < 6 ? cW2 + (slot - 3) * 16384
                         : slot == 6 ? rW1 : rW2;
        Wt[slot * 16384 + n * 128 + k] = f2b(src[wi]);
    } else if (gid < 9 * 16384) {
        int j = gid - 8 * 16384;
        int n = j >> 7, k = j & 127;
        Wt[8 * 16384 + j] = (n < 4) ? f2b(rW3[k * 4 + n]) : (u16)0;
    }
    // task 3: zeroing (blocks 0..230)
    if (gid < NN) deg[gid] = 0;
    int j2 = gid - NN;
    if (j2 >= 0 && j2 < BB * CH) pooled[j2] = 0.f;
    int k2 = j2 - BB * CH;
    if (k2 >= 0 && k2 < 3 * 256) gstats[k2] = 0.f;
}

__global__ __launch_bounds__(256) void k_count(const int* __restrict__ ei,
                                               int* __restrict__ deg) {
    int e = blockIdx.x * 256 + threadIdx.x;
    if (e < EE) atomicAdd(&deg[ei[EE + e]], 1);
}

// stage A: per-block (256 elems) sum of deg -> bsum[blk]
__global__ __launch_bounds__(256) void k_scanA(const int* __restrict__ deg,
                                               int* __restrict__ bsum) {
    __shared__ int sm[256];
    int i = blockIdx.x * 256 + threadIdx.x;
    sm[threadIdx.x] = (i < NN) ? deg[i] : 0;
    __syncthreads();
    for (int off = 128; off > 0; off >>= 1) {
        if (threadIdx.x < off) sm[threadIdx.x] += sm[threadIdx.x + off];
        __syncthreads();
    }
    if (threadIdx.x == 0) bsum[blockIdx.x] = sm[0];
}

// stage B: scan bsum in LDS -> block offset; local scan -> rowptr & cur
__global__ __launch_bounds__(256) void k_scanB(const int* __restrict__ deg,
                                               const int* __restrict__ bsum,
                                               int* __restrict__ rowptr,
                                               int* __restrict__ cur) {
    __shared__ int sb[256], sd[256];
    int t = threadIdx.x;
    sb[t] = (t < NSB) ? bsum[t] : 0;
    __syncthreads();
    for (int off = 1; off < 256; off <<= 1) {
        int v = (t >= off) ? sb[t - off] : 0;
        __syncthreads();
        sb[t] += v;
        __syncthreads();
    }
    int blockOff = (blockIdx.x == 0) ? 0 : sb[blockIdx.x - 1];
    int i = blockIdx.x * 256 + t;
    int d = (i < NN) ? deg[i] : 0;
    sd[t] = d;
    __syncthreads();
    for (int off = 1; off < 256; off <<= 1) {
        int v = (t >= off) ? sd[t - off] : 0;
        __syncthreads();
        sd[t] += v;
        __syncthreads();
    }
    int excl = blockOff + sd[t] - d;
    if (i < NN) { rowptr[i] = excl; cur[i] = excl; }
    if (i == NN - 1) rowptr[NN] = excl + d;
}

__global__ __launch_bounds__(256) void k_fill(const int* __restrict__ ei,
                                              int* __restrict__ cur,
                                              int* __restrict__ perm) {
    int e = blockIdx.x * 256 + threadIdx.x;
    if (e < EE) {
        int dst = ei[EE + e];
        int idx = atomicAdd(&cur[dst], 1);
        perm[idx] = ei[e];
    }
}

// ---------------------------------------------------------------------------
// Gather: y[dst] = bf16( x[dst] + sum_{src} x[src] ), wave-uniform version.
// One dst per 64-lane wave (lane = 2 cols, u32 loads; each edge = one
// coalesced 256B read). Loop bounds + perm indices wave-uniform -> zero
// divergence waste, scalar perm loads. 4-deep unroll for MLP.
// ---------------------------------------------------------------------------
__global__ __launch_bounds__(256) void k_gather(const u16* __restrict__ x,
                                                const int* __restrict__ rowptr,
                                                const int* __restrict__ perm,
                                                u16* __restrict__ y) {
    int dst = blockIdx.x * 4 + (threadIdx.x >> 6);
    int c2 = (threadIdx.x & 63) * 2;
    const u16* xb = x + c2;
    u32 self = *(const u32*)(x + (long)dst * CH + c2);
    float a0 = b2f((u16)self), a1 = b2f((u16)(self >> 16));
    float p0 = 0.f, p1 = 0.f, q0 = 0.f, q1 = 0.f;
    float r0 = 0.f, r1 = 0.f, t0 = 0.f, t1 = 0.f;
    int beg = rowptr[dst], end = rowptr[dst + 1];
    int e = beg;
    for (; e + 3 < end; e += 4) {
        int i0 = perm[e], i1 = perm[e + 1], i2 = perm[e + 2], i3 = perm[e + 3];
        u32 v0 = *(const u32*)(xb + (long)i0 * CH);
        u32 v1 = *(const u32*)(xb + (long)i1 * CH);
        u32 v2 = *(const u32*)(xb + (long)i2 * CH);
        u32 v3 = *(const u32*)(xb + (long)i3 * CH);
        p0 += b2f((u16)v0); p1 += b2f((u16)(v0 >> 16));
        q0 += b2f((u16)v1); q1 += b2f((u16)(v1 >> 16));
        r0 += b2f((u16)v2); r1 += b2f((u16)(v2 >> 16));
        t0 += b2f((u16)v3); t1 += b2f((u16)(v3 >> 16));
    }
    for (; e < end; ++e) {
        int i0 = perm[e];
        u32 v0 = *(const u32*)(xb + (long)i0 * CH);
        a0 += b2f((u16)v0); a1 += b2f((u16)(v0 >> 16));
    }
    a0 += (p0 + q0) + (r0 + t0);
    a1 += (p1 + q1) + (r1 + t1);
    u32 o = (u32)f2b(a0) | ((u32)f2b(a1) << 16);
    *(u32*)(y + (long)dst * CH + c2) = o;
}

// ---------------------------------------------------------------------------
// Shared GEMM building blocks (layouts verified m89/m91; XOR-swizzle c^(r&15))
// ---------------------------------------------------------------------------
__device__ __forceinline__ void stageB8(const u16* __restrict__ Wt, u16* sB,
                                        int s, int rr) {
#pragma unroll
    for (int it = 0; it < 8; ++it) {
        int n = it * 16 + rr;
        uint4 u = *(const uint4*)(Wt + n * CH + 8 * s);
        *(uint4*)(&sB[n * CH + ((s ^ (n & 15)) * 8)]) = u;
    }
}

template <int M>
__device__ __forceinline__ void mfmaT(const u16* sA, const u16* sB,
                                      f32x4 (&acc)[M][8], int rowbase, int quad,
                                      int l16) {
    f32x4 z = {0.f, 0.f, 0.f, 0.f};
#pragma unroll
    for (int m = 0; m < M; ++m)
#pragma unroll
        for (int t = 0; t < 8; ++t) acc[m][t] = z;
#pragma unroll
    for (int kc = 0; kc < 4; ++kc) {
        int off = (((kc << 2) | quad) ^ l16) << 3;
        s16x8 a[M];
#pragma unroll
        for (int m = 0; m < M; ++m)
            a[m] = *(const s16x8*)(sA + (rowbase + m * 16 + l16) * CH + off);
#pragma unroll
        for (int t = 0; t < 8; ++t) {
            s16x8 bfr = *(const s16x8*)(sB + (t * 16 + l16) * CH + off);
#pragma unroll
            for (int m = 0; m < M; ++m)
                acc[m][t] = __builtin_amdgcn_mfma_f32_16x16x32_bf16(a[m], bfr, acc[m][t], 0, 0, 0);
        }
    }
}

template <int M>
__device__ __forceinline__ void biasreluT(f32x4 (&acc)[M][8],
                                          const float* __restrict__ bias, int l16) {
#pragma unroll
    for (int t = 0; t < 8; ++t) {
        float bv = bias[t * 16 + l16];
#pragma unroll
        for (int m = 0; m < M; ++m)
#pragma unroll
            for (int r = 0; r < 4; ++r)
                acc[m][t][r] = fmaxf(acc[m][t][r] + bv, 0.f);
    }
}

// write C tile (in acc) back into sA as bf16 with the A-read XOR-swizzle.
template <int M>
__device__ __forceinline__ void restageT(const f32x4 (&acc)[M][8], u16* sA,
                                         int rowbase, int quad, int l16) {
#pragma unroll
    for (int t = 0; t < 8; ++t) {
        int chunk = (t << 1) | (l16 >> 3);
        int o7 = l16 & 7;
#pragma unroll
        for (int m = 0; m < M; ++m)
#pragma unroll
            for (int r = 0; r < 4; ++r) {
                int lr = rowbase + m * 16 + quad * 4 + r;
                sA[lr * CH + ((chunk ^ (lr & 15)) << 3) + o7] = f2b(acc[m][t][r]);
            }
    }
}

// ---------------------------------------------------------------------------
// k_gemm1: h = y@W1 + b1 ; block stat partials -> atomicAdd gstats ;
// h -> h16 (bf16, pre-BN). TR=64 rows/block, 3 blocks/CU.
// ---------------------------------------------------------------------------
__global__ __launch_bounds__(256, 3) void k_gemm1(
    const u16* __restrict__ y16, const u16* __restrict__ Wt, int layer,
    const float* __restrict__ cb1, float* __restrict__ gstats,
    u16* __restrict__ h16) {
    __shared__ u16 sA[TR * CH];
    __shared__ u16 sB[128 * CH];
    const int tid = threadIdx.x;
    const int s = tid & 15, rr = tid >> 4;
    const int r0 = blockIdx.x * TR;
    const int lane = tid & 63, wv = tid >> 6, quad = lane >> 4, l16 = lane & 15;

    stageB8(Wt + layer * 16384, sB, s, rr);
#pragma unroll
    for (int it = 0; it < 4; ++it) {
        int lr = it * 16 + rr, gr = r0 + lr;
        union { u16 pk[8]; uint4 v; } uu;
        if (gr < NN) {
            uu.v = *(const uint4*)(y16 + (long)gr * CH + 8 * s);
        } else {
#pragma unroll
            for (int j = 0; j < 8; ++j) uu.pk[j] = 0;
        }
        *(uint4*)(&sA[lr * CH + ((s ^ (lr & 15)) * 8)]) = uu.v;
    }
    __syncthreads();

    f32x4 acc[1][8];
    mfmaT<1>(sA, sB, acc, wv * 16, quad, l16);

    // bias add (h pre-relu kept in acc) + stats over valid rows
    float ss[8], qq[8];
#pragma unroll
    for (int t = 0; t < 8; ++t) {
        float bv = cb1[t * 16 + l16];
        ss[t] = 0.f; qq[t] = 0.f;
        int rbase = r0 + wv * 16 + quad * 4;
#pragma unroll
        for (int r = 0; r < 4; ++r) {
            float v = acc[0][t][r] + bv;
            acc[0][t][r] = v;
            if (rbase + r < NN) { ss[t] += v; qq[t] += v * v; }
        }
    }
#pragma unroll
    for (int t = 0; t < 8; ++t) {
        ss[t] += __shfl_xor(ss[t], 16);
        ss[t] += __shfl_xor(ss[t], 32);
        qq[t] += __shfl_xor(qq[t], 16);
        qq[t] += __shfl_xor(qq[t], 32);
    }

    // write h (pre-BN, bf16) to h16 — global stores fly while we reduce
#pragma unroll
    for (int t = 0; t < 8; ++t) {
        int col = t * 16 + l16;
#pragma unroll
        for (int r = 0; r < 4; ++r) {
            int row = r0 + wv * 16 + quad * 4 + r;
            if (row < NN) h16[(long)row * CH + col] = f2b(acc[0][t][r]);
        }
    }

    float* red = (float*)sA;
    __syncthreads();  // all waves done reading sA in mfmaT
    if (lane < 16) {
#pragma unroll
        for (int t = 0; t < 8; ++t) {
            red[wv * 256 + t * 16 + l16] = ss[t];
            red[wv * 256 + 128 + t * 16 + l16] = qq[t];
        }
    }
    __syncthreads();
    unsafeAtomicAdd(&gstats[tid],
                    red[tid] + red[256 + tid] + red[512 + tid] + red[768 + tid]);
}

// ---------------------------------------------------------------------------
// k_gemm2: sc/sh from gstats (plain loads — kernel-boundary coherence);
// BN+ReLU folded into the A-stage bf16 conversion; GEMM2 -> xc.
// LAST: tile-resident rec1/rec2/rec3 -> x_rec.
// ---------------------------------------------------------------------------
template <bool LAST>
__global__ __launch_bounds__(256, 3) void k_gemm2(
    const u16* __restrict__ h16, const u16* __restrict__ Wt, int layer,
    const float* __restrict__ g, const float* __restrict__ bbeta,
    const float* __restrict__ gstats, const float* __restrict__ cb2,
    u16* __restrict__ xc,
    const float* __restrict__ rb1, const float* __restrict__ rb2,
    const float* __restrict__ rb3, float* __restrict__ x_rec) {
    __shared__ u16 sA[TR * CH];
    __shared__ u16 sB[128 * CH];
    __shared__ float snorm[256];  // sc[128], sh[128]
    const int tid = threadIdx.x;
    const int s = tid & 15, rr = tid >> 4;
    const int r0 = blockIdx.x * TR;
    const int lane = tid & 63, wv = tid >> 6, quad = lane >> 4, l16 = lane & 15;

    if (tid < 128) {
        float sum = gstats[tid];
        float sq = gstats[128 + tid];
        float mu = sum / (float)NN;
        float var = sq / (float)NN - mu * mu;
        float sc = g[tid] * rsqrtf(var + 1e-5f);
        snorm[tid] = sc;
        snorm[128 + tid] = bbeta[tid] - mu * sc;
    }
    stageB8(Wt + (3 + layer) * 16384, sB, s, rr);
    __syncthreads();  // snorm ready

#pragma unroll
    for (int it = 0; it < 4; ++it) {
        int lr = it * 16 + rr, gr = r0 + lr;
        union { u16 pk[8]; uint4 v; } uu;
        if (gr < NN) {
            uu.v = *(const uint4*)(h16 + (long)gr * CH + 8 * s);
#pragma unroll
            for (int j = 0; j < 8; ++j) {
                int c = 8 * s + j;
                float v = fmaxf(b2f(uu.pk[j]) * snorm[c] + snorm[128 + c], 0.f);
                uu.pk[j] = f2b(v);
            }
        } else {
#pragma unroll
            for (int j = 0; j < 8; ++j) uu.pk[j] = 0;
        }
        *(uint4*)(&sA[lr * CH + ((s ^ (lr & 15)) * 8)]) = uu.v;
    }
    __syncthreads();
    f32x4 acc[1][8];
    mfmaT<1>(sA, sB, acc, wv * 16, quad, l16);
    biasreluT<1>(acc, cb2, l16);
#pragma unroll
    for (int t = 0; t < 8; ++t) {
        int col = t * 16 + l16;
#pragma unroll
        for (int r = 0; r < 4; ++r) {
            int row = r0 + wv * 16 + quad * 4 + r;
            if (row < NN) xc[(long)row * CH + col] = f2b(acc[0][t][r]);
        }
    }

    if constexpr (LAST) {
        // ---- rec1 ----
        __syncthreads();
        restageT<1>(acc, sA, wv * 16, quad, l16);
        stageB8(Wt + 6 * 16384, sB, s, rr);
        __syncthreads();
        mfmaT<1>(sA, sB, acc, wv * 16, quad, l16);
        biasreluT<1>(acc, rb1, l16);
        // ---- rec2 ----
        __syncthreads();
        restageT<1>(acc, sA, wv * 16, quad, l16);
        stageB8(Wt + 7 * 16384, sB, s, rr);
        __syncthreads();
        mfmaT<1>(sA, sB, acc, wv * 16, quad, l16);
        biasreluT<1>(acc, rb2, l16);
        // ---- rec3 (N=4, one 16-col tile) ----
        __syncthreads();
        restageT<1>(acc, sA, wv * 16, quad, l16);
        {
            int n = rr;  // 16 B-rows
            uint4 u = *(const uint4*)(Wt + 8 * 16384 + n * CH + 8 * s);
            *(uint4*)(&sB[n * CH + ((s ^ (n & 15)) * 8)]) = u;
        }
        __syncthreads();
        f32x4 a4 = {0.f, 0.f, 0.f, 0.f};
        const u16* pa0 = sA + (wv * 16 + l16) * CH;
#pragma unroll
        for (int kc = 0; kc < 4; ++kc) {
            int off = (((kc << 2) | quad) ^ l16) << 3;
            s16x8 a0 = *(const s16x8*)(pa0 + off);
            s16x8 bfr = *(const s16x8*)(sB + l16 * CH + off);
            a4 = __builtin_amdgcn_mfma_f32_16x16x32_bf16(a0, bfr, a4, 0, 0, 0);
        }
        if (l16 < 4) {
            float bv = rb3[l16];
#pragma unroll
            for (int r = 0; r < 4; ++r) {
                int row = r0 + wv * 16 + quad * 4 + r;
                if (row < NN) x_rec[(long)row * 4 + l16] = fmaxf(a4[r] + bv, 0.f);
            }
        }
    }
}

// ---------------------------------------------------------------------------
// global_add_pool, parallel: 392 blocks x 128 rows; run-length accumulate.
// ---------------------------------------------------------------------------
__global__ __launch_bounds__(256) void k_pool(const u16* __restrict__ x,
                                              const int* __restrict__ batch,
                                              float* __restrict__ pooled) {
    int r0 = blockIdx.x * 128;
    if (r0 >= NN) return;
    int rend = r0 + 128 < NN ? r0 + 128 : NN;
    int c = threadIdx.x & 127;
    int half = threadIdx.x >> 7;
    int r = r0 + half;
    if (r >= rend) return;
    int g = batch[r];
    float s = 0.f;
    for (; r < rend; r += 2) {
        int gg = batch[r];
        if (gg != g) {
            unsafeAtomicAdd(pooled + g * CH + c, s);
            s = 0.f;
            g = gg;
        }
        s += b2f(x[(long)r * CH + c]);
    }
    unsafeAtomicAdd(pooled + g * CH + c, s);
}

// out[b] = relu(pooled[b] @ W1 + b1) @ W2 + b2  ; grid 64 x 128, all f32
__global__ __launch_bounds__(128) void k_mlp(const float* __restrict__ pooled,
                                             const float* __restrict__ W1,
                                             const float* __restrict__ b1,
                                             const float* __restrict__ W2,
                                             const float* __restrict__ b2,
                                             float* __restrict__ out) {
    __shared__ float p[128], t1[128];
    int b = blockIdx.x, t = threadIdx.x;
    p[t] = pooled[b * CH + t];
    __syncthreads();
    float acc = b1[t];
    for (int k = 0; k < 128; ++k) acc += p[k] * W1[k * 128 + t];
    t1[t] = fmaxf(acc, 0.f);
    __syncthreads();
    if (t < 64) {
        float o = b2[t];
        for (int k = 0; k < 128; ++k) o += t1[k] * W2[k * 64 + t];
        out[b * 64 + t] = o;
    }
}

// ---------------------------------------------------------------------------
extern "C" void kernel_launch(void* const* d_in, const int* in_sizes, int n_in,
                              void* d_out, int out_size, void* d_ws, size_t ws_size,
                              hipStream_t stream) {
    const float* x_in   = (const float*)d_in[0];
    const int*   ei     = (const int*)d_in[1];
    const int*   batch  = (const int*)d_in[2];
    const float* convW1 = (const float*)d_in[3];
    const float* convb1 = (const float*)d_in[4];
    const float* bn_g   = (const float*)d_in[5];
    const float* bn_b   = (const float*)d_in[6];
    const float* convW2 = (const float*)d_in[7];
    const float* convb2 = (const float*)d_in[8];
    const float* recW1  = (const float*)d_in[9];
    const float* recb1  = (const float*)d_in[10];
    const float* recW2  = (const float*)d_in[11];
    const float* recb2  = (const float*)d_in[12];
    const float* recW3  = (const float*)d_in[13];
    const float* recb3  = (const float*)d_in[14];
    const float* mlpW1  = (const float*)d_in[15];
    const float* mlpb1  = (const float*)d_in[16];
    const float* mlpW2  = (const float*)d_in[17];
    const float* mlpb2  = (const float*)d_in[18];

    float* out   = (float*)d_out;      // [64*64] out, then [50000*4] x_rec
    float* x_rec = out + 4096;

    char* w = (char*)d_ws;
    u16*   x16    = (u16*)w;    w += (size_t)NN * CH * 2;      // bf16 copy of x_in
    u16*   y16    = (u16*)w;    w += (size_t)NN * CH * 2;      // gather output
    u16*   h16    = (u16*)w;    w += (size_t)NN * CH * 2;      // GEMM1 output (pre-BN)
    u16*   xc     = (u16*)w;    w += (size_t)NN * CH * 2;      // layer output
    u16*   Wt     = (u16*)w;    w += (size_t)9 * 16384 * 2;    // transposed bf16 weights
    float* gstats = (float*)w;  w += (size_t)3 * 256 * 4;      // BN sums per layer
    float* pooled = (float*)w;  w += (size_t)BB * CH * 4;
    int*   deg    = (int*)w;    w += (size_t)NN * 4;
    int*   bsum   = (int*)w;    w += (size_t)NSB * 4;
    int*   rowptr = (int*)w;    w += (size_t)(NN + 1) * 4;
    int*   cur    = (int*)w;    w += (size_t)NN * 4;
    int*   perm   = (int*)w;    w += (size_t)EE * 4;

    dim3 b256(256), b128(128);

    // prep (zero + cvt + transpose) then CSR build
    k_prep<<<3125, b256, 0, stream>>>(x_in, x16, convW1, convW2, recW1, recW2,
                                      recW3, Wt, deg, pooled, gstats);
    k_count<<<2344, b256, 0, stream>>>(ei, deg);
    k_scanA<<<NSB, b256, 0, stream>>>(deg, bsum);
    k_scanB<<<NSB, b256, 0, stream>>>(deg, bsum, rowptr, cur);
    k_fill<<<2344, b256, 0, stream>>>(ei, cur, perm);

    const u16* cur_x = x16;
    for (int l = 0; l < LL; ++l) {
        k_gather<<<NGA, b256, 0, stream>>>(cur_x, rowptr, perm, y16);
        k_gemm1<<<NGB, b256, 0, stream>>>(y16, Wt, l, convb1 + l * 128,
                                          gstats + l * 256, h16);
        if (l < LL - 1)
            k_gemm2<false><<<NGB, b256, 0, stream>>>(
                h16, Wt, l, bn_g + l * 128, bn_b + l * 128, gstats + l * 256,
                convb2 + l * 128, xc, recb1, recb2, recb3, x_rec);
        else
            k_gemm2<true><<<NGB, b256, 0, stream>>>(
                h16, Wt, l, bn_g + l * 128, bn_b + l * 128, gstats + l * 256,
                convb2 + l * 128, xc, recb1, recb2, recb3, x_rec);
        cur_x = xc;
    }
    // pooling + final MLP
    k_pool<<<NPB, b256, 0, stream>>>(xc, batch, pooled);
    k_mlp<<<64, b128, 0, stream>>>(pooled, mlpW1, mlpb1, mlpW2, mlpb2, out);
}

// Round 4
// 376.751 us; speedup vs baseline: 1.2638x; 1.1260x over previous
//
#include <hip/hip_runtime.h>

#define NN 50000
#define EE 600000
#define BB 64
#define CH 128
#define LL 3
#define NGB 391   // GEMM/layer row-blocks = ceil(50000/128)
#define NSB 196   // scan blocks = ceil(50000/256)
#define NPB 392   // pool blocks = ceil(50000/128)

typedef unsigned short u16;
typedef unsigned int u32;
typedef short s16x8 __attribute__((ext_vector_type(8)));
typedef float f32x4 __attribute__((ext_vector_type(4)));

__device__ __forceinline__ u16 f2b(float f) {
    u32 x = __float_as_uint(f);
    return (u16)((x + 0x7FFFu + ((x >> 16) & 1u)) >> 16);  // RNE f32->bf16
}
__device__ __forceinline__ float b2f(u16 u) {
    return __uint_as_float(((u32)u) << 16);
}

// ---------------------------------------------------------------------------
// k_prep: fused zero (deg/pooled/gstats) + x->bf16 cvt + weight transpose.
// grid 3125 x 256. All three tasks independent; range-dispatch by gid.
// slots 0-2: convW1[l], 3-5: convW2[l], 6: recW1, 7: recW2, 8: recW3 (zero-pad)
// ---------------------------------------------------------------------------
__global__ __launch_bounds__(256) void k_prep(
    const float* __restrict__ x, u16* __restrict__ x16,
    const float* __restrict__ cW1, const float* __restrict__ cW2,
    const float* __restrict__ rW1, const float* __restrict__ rW2,
    const float* __restrict__ rW3, u16* __restrict__ Wt,
    int* __restrict__ deg, float* __restrict__ pooled,
    float* __restrict__ gstats) {
    int gid = blockIdx.x * 256 + threadIdx.x;

    // task 1: cvt (all blocks)
    long base = (long)gid * 8;
    if (base < (long)NN * CH) {
        float4 f0 = *(const float4*)(x + base);
        float4 f1 = *(const float4*)(x + base + 4);
        union { u16 pk[8]; uint4 v; } uu;
        uu.pk[0] = f2b(f0.x); uu.pk[1] = f2b(f0.y);
        uu.pk[2] = f2b(f0.z); uu.pk[3] = f2b(f0.w);
        uu.pk[4] = f2b(f1.x); uu.pk[5] = f2b(f1.y);
        uu.pk[6] = f2b(f1.z); uu.pk[7] = f2b(f1.w);
        *(uint4*)(x16 + base) = uu.v;
    }
    // task 2: weight transpose (gid < 9*16384)
    if (gid < 8 * 16384) {
        int slot = gid >> 14;
        int wi = gid & 16383;
        int k = wi >> 7, n = wi & 127;
        const float* src = slot < 3 ? cW1 + slot * 16384
                         : slot < 6 ? cW2 + (slot - 3) * 16384
                         : slot == 6 ? rW1 : rW2;
        Wt[slot * 16384 + n * 128 + k] = f2b(src[wi]);
    } else if (gid < 9 * 16384) {
        int j = gid - 8 * 16384;
        int n = j >> 7, k = j & 127;
        Wt[8 * 16384 + j] = (n < 4) ? f2b(rW3[k * 4 + n]) : (u16)0;
    }
    // task 3: zeroing
    if (gid < NN) deg[gid] = 0;
    int j2 = gid - NN;
    if (j2 >= 0 && j2 < BB * CH) pooled[j2] = 0.f;
    int k2 = j2 - BB * CH;
    if (k2 >= 0 && k2 < 3 * 256) gstats[k2] = 0.f;
}

__global__ __launch_bounds__(256) void k_count(const int* __restrict__ ei,
                                               int* __restrict__ deg) {
    int e = blockIdx.x * 256 + threadIdx.x;
    if (e < EE) atomicAdd(&deg[ei[EE + e]], 1);
}

// stage A: per-block (256 elems) sum of deg -> bsum[blk]
__global__ __launch_bounds__(256) void k_scanA(const int* __restrict__ deg,
                                               int* __restrict__ bsum) {
    __shared__ int sm[256];
    int i = blockIdx.x * 256 + threadIdx.x;
    sm[threadIdx.x] = (i < NN) ? deg[i] : 0;
    __syncthreads();
    for (int off = 128; off > 0; off >>= 1) {
        if (threadIdx.x < off) sm[threadIdx.x] += sm[threadIdx.x + off];
        __syncthreads();
    }
    if (threadIdx.x == 0) bsum[blockIdx.x] = sm[0];
}

// stage B: scan bsum in LDS -> block offset; local scan -> rowptr & cur
__global__ __launch_bounds__(256) void k_scanB(const int* __restrict__ deg,
                                               const int* __restrict__ bsum,
                                               int* __restrict__ rowptr,
                                               int* __restrict__ cur) {
    __shared__ int sb[256], sd[256];
    int t = threadIdx.x;
    sb[t] = (t < NSB) ? bsum[t] : 0;
    __syncthreads();
    for (int off = 1; off < 256; off <<= 1) {
        int v = (t >= off) ? sb[t - off] : 0;
        __syncthreads();
        sb[t] += v;
        __syncthreads();
    }
    int blockOff = (blockIdx.x == 0) ? 0 : sb[blockIdx.x - 1];
    int i = blockIdx.x * 256 + t;
    int d = (i < NN) ? deg[i] : 0;
    sd[t] = d;
    __syncthreads();
    for (int off = 1; off < 256; off <<= 1) {
        int v = (t >= off) ? sd[t - off] : 0;
        __syncthreads();
        sd[t] += v;
        __syncthreads();
    }
    int excl = blockOff + sd[t] - d;
    if (i < NN) { rowptr[i] = excl; cur[i] = excl; }
    if (i == NN - 1) rowptr[NN] = excl + d;
}

__global__ __launch_bounds__(256) void k_fill(const int* __restrict__ ei,
                                              int* __restrict__ cur,
                                              int* __restrict__ perm) {
    int e = blockIdx.x * 256 + threadIdx.x;
    if (e < EE) {
        int dst = ei[EE + e];
        int idx = atomicAdd(&cur[dst], 1);
        perm[idx] = ei[e];
    }
}

// ---------------------------------------------------------------------------
// Gather: y[dst] = bf16( x[dst] + sum_{src} x[src] ), bf16 in, f32 accum.
// One dst per 16-lane group (uint4 = 8 bf16/lane); 4-way unrolled edge loop
// with 4 independent accumulator sets -> 16 loads in flight per wave.
// ---------------------------------------------------------------------------
__global__ __launch_bounds__(256) void k_gather(const u16* __restrict__ x,
                                                const int* __restrict__ rowptr,
                                                const int* __restrict__ perm,
                                                u16* __restrict__ y) {
    int dst = blockIdx.x * 16 + (threadIdx.x >> 4);
    int lane = threadIdx.x & 15;
    int co = lane * 8;
    int beg = rowptr[dst], end = rowptr[dst + 1];
    union { u16 pk[8]; uint4 v; } uu;
    uu.v = *(const uint4*)(x + (long)dst * CH + co);
    float a[8], b[8], c[8], d[8];
#pragma unroll
    for (int j = 0; j < 8; ++j) { a[j] = b2f(uu.pk[j]); b[j] = 0.f; c[j] = 0.f; d[j] = 0.f; }
    int e = beg;
    for (; e + 3 < end; e += 4) {
        int s0 = perm[e], s1 = perm[e + 1], s2 = perm[e + 2], s3 = perm[e + 3];
        union { u16 pk[8]; uint4 v; } v0, v1, v2, v3;
        v0.v = *(const uint4*)(x + (long)s0 * CH + co);
        v1.v = *(const uint4*)(x + (long)s1 * CH + co);
        v2.v = *(const uint4*)(x + (long)s2 * CH + co);
        v3.v = *(const uint4*)(x + (long)s3 * CH + co);
#pragma unroll
        for (int j = 0; j < 8; ++j) {
            a[j] += b2f(v0.pk[j]); b[j] += b2f(v1.pk[j]);
            c[j] += b2f(v2.pk[j]); d[j] += b2f(v3.pk[j]);
        }
    }
    for (; e < end; ++e) {
        int s0 = perm[e];
        union { u16 pk[8]; uint4 v; } v0;
        v0.v = *(const uint4*)(x + (long)s0 * CH + co);
#pragma unroll
        for (int j = 0; j < 8; ++j) a[j] += b2f(v0.pk[j]);
    }
    union { u16 pk[8]; uint4 v; } ov;
#pragma unroll
    for (int j = 0; j < 8; ++j) ov.pk[j] = f2b((a[j] + b[j]) + (c[j] + d[j]));
    *(uint4*)(y + (long)dst * CH + co) = ov.v;
}

// ---------------------------------------------------------------------------
// Shared GEMM building blocks (layouts verified m89/m91; XOR-swizzle c^(r&15))
// ---------------------------------------------------------------------------
__device__ __forceinline__ void stageB8(const u16* __restrict__ Wt, u16* sB,
                                        int s, int rr) {
#pragma unroll
    for (int it = 0; it < 8; ++it) {
        int n = it * 16 + rr;
        uint4 u = *(const uint4*)(Wt + n * CH + 8 * s);
        *(uint4*)(&sB[n * CH + ((s ^ (n & 15)) * 8)]) = u;
    }
}

__device__ __forceinline__ void mfma8(const u16* sA, const u16* sB,
                                      f32x4 acc[2][8], int wv, int quad, int l16) {
    f32x4 z = {0.f, 0.f, 0.f, 0.f};
#pragma unroll
    for (int m = 0; m < 2; ++m)
#pragma unroll
        for (int t = 0; t < 8; ++t) acc[m][t] = z;
    const u16* pa0 = sA + (wv * 32 + l16) * CH;
    const u16* pa1 = pa0 + 16 * CH;
#pragma unroll
    for (int kc = 0; kc < 4; ++kc) {
        int off = (((kc << 2) | quad) ^ l16) << 3;
        s16x8 a0 = *(const s16x8*)(pa0 + off);
        s16x8 a1 = *(const s16x8*)(pa1 + off);
#pragma unroll
        for (int t = 0; t < 8; ++t) {
            s16x8 bfr = *(const s16x8*)(sB + (t * 16 + l16) * CH + off);
            acc[0][t] = __builtin_amdgcn_mfma_f32_16x16x32_bf16(a0, bfr, acc[0][t], 0, 0, 0);
            acc[1][t] = __builtin_amdgcn_mfma_f32_16x16x32_bf16(a1, bfr, acc[1][t], 0, 0, 0);
        }
    }
}

__device__ __forceinline__ void biasrelu(f32x4 acc[2][8],
                                         const float* __restrict__ bias, int l16) {
#pragma unroll
    for (int t = 0; t < 8; ++t) {
        float bv = bias[t * 16 + l16];
#pragma unroll
        for (int m = 0; m < 2; ++m)
#pragma unroll
            for (int r = 0; r < 4; ++r)
                acc[m][t][r] = fmaxf(acc[m][t][r] + bv, 0.f);
    }
}

// write C tile (in acc) back into sA as bf16 with the A-read XOR-swizzle.
__device__ __forceinline__ void restage(const f32x4 acc[2][8], u16* sA,
                                        int wv, int quad, int l16) {
#pragma unroll
    for (int t = 0; t < 8; ++t) {
        int chunk = (t << 1) | (l16 >> 3);
        int o7 = l16 & 7;
#pragma unroll
        for (int m = 0; m < 2; ++m)
#pragma unroll
            for (int r = 0; r < 4; ++r) {
                int lr = wv * 32 + m * 16 + quad * 4 + r;
                sA[lr * CH + ((chunk ^ (lr & 15)) << 3) + o7] = f2b(acc[m][t][r]);
            }
    }
}

// ---------------------------------------------------------------------------
// k_gemm1: h = y@W1 + b1 ; block stat partials -> atomicAdd gstats ;
// h written back IN PLACE over y16 as bf16 (block reads rows [r0,r0+128)
// before writing the same rows -> race-free). 128 rows/block, 2 blocks/CU.
// ---------------------------------------------------------------------------
__global__ __launch_bounds__(256, 2) void k_gemm1(
    u16* __restrict__ hy, const u16* __restrict__ Wt, int layer,
    const float* __restrict__ cb1, float* __restrict__ gstats) {
    __shared__ u16 sA[128 * CH];
    __shared__ u16 sB[128 * CH];
    const int tid = threadIdx.x;
    const int s = tid & 15, rr = tid >> 4;
    const int r0 = blockIdx.x * 128;
    const int lane = tid & 63, wv = tid >> 6, quad = lane >> 4, l16 = lane & 15;

    stageB8(Wt + layer * 16384, sB, s, rr);
#pragma unroll
    for (int it = 0; it < 8; ++it) {
        int lr = it * 16 + rr, gr = r0 + lr;
        union { u16 pk[8]; uint4 v; } uu;
        if (gr < NN) {
            uu.v = *(const uint4*)(hy + (long)gr * CH + 8 * s);
        } else {
#pragma unroll
            for (int j = 0; j < 8; ++j) uu.pk[j] = 0;
        }
        *(uint4*)(&sA[lr * CH + ((s ^ (lr & 15)) * 8)]) = uu.v;
    }
    __syncthreads();
    f32x4 acc[2][8];
    mfma8(sA, sB, acc, wv, quad, l16);

    // bias add (h pre-relu kept in acc) + stats over valid rows
    float ss[8], qq[8];
#pragma unroll
    for (int t = 0; t < 8; ++t) {
        float bv = cb1[t * 16 + l16];
        ss[t] = 0.f; qq[t] = 0.f;
#pragma unroll
        for (int m = 0; m < 2; ++m) {
            int rbase = r0 + wv * 32 + m * 16 + quad * 4;
#pragma unroll
            for (int r = 0; r < 4; ++r) {
                float v = acc[m][t][r] + bv;
                acc[m][t][r] = v;
                if (rbase + r < NN) { ss[t] += v; qq[t] += v * v; }
            }
        }
    }
#pragma unroll
    for (int t = 0; t < 8; ++t) {
        ss[t] += __shfl_xor(ss[t], 16);
        ss[t] += __shfl_xor(ss[t], 32);
        qq[t] += __shfl_xor(qq[t], 16);
        qq[t] += __shfl_xor(qq[t], 32);
    }
    float* red = (float*)sA;
    __syncthreads();  // all waves done reading sA in mfma8
    if (lane < 16) {
#pragma unroll
        for (int t = 0; t < 8; ++t) {
            red[wv * 256 + t * 16 + l16] = ss[t];
            red[wv * 256 + 128 + t * 16 + l16] = qq[t];
        }
    }
    __syncthreads();
    unsafeAtomicAdd(&gstats[tid],
                    red[tid] + red[256 + tid] + red[512 + tid] + red[768 + tid]);

    // write h (pre-BN, bf16) back in place
#pragma unroll
    for (int t = 0; t < 8; ++t) {
        int col = t * 16 + l16;
#pragma unroll
        for (int m = 0; m < 2; ++m)
#pragma unroll
            for (int r = 0; r < 4; ++r) {
                int row = r0 + wv * 32 + m * 16 + quad * 4 + r;
                if (row < NN) hy[(long)row * CH + col] = f2b(acc[m][t][r]);
            }
    }
}

// ---------------------------------------------------------------------------
// k_gemm2: sc/sh from gstats (plain loads — kernel-boundary coherence);
// BN+ReLU folded into the A-stage bf16 conversion; GEMM2 -> xc.
// LAST: tile-resident rec1/rec2/rec3 -> x_rec.
// ---------------------------------------------------------------------------
template <bool LAST>
__global__ __launch_bounds__(256, 2) void k_gemm2(
    const u16* __restrict__ h16, const u16* __restrict__ Wt, int layer,
    const float* __restrict__ g, const float* __restrict__ bbeta,
    const float* __restrict__ gstats, const float* __restrict__ cb2,
    u16* __restrict__ xc,
    const float* __restrict__ rb1, const float* __restrict__ rb2,
    const float* __restrict__ rb3, float* __restrict__ x_rec) {
    __shared__ u16 sA[128 * CH];
    __shared__ u16 sB[128 * CH];
    __shared__ float snorm[256];  // sc[128], sh[128]
    const int tid = threadIdx.x;
    const int s = tid & 15, rr = tid >> 4;
    const int r0 = blockIdx.x * 128;
    const int lane = tid & 63, wv = tid >> 6, quad = lane >> 4, l16 = lane & 15;

    if (tid < 128) {
        float sum = gstats[tid];
        float sq = gstats[128 + tid];
        float mu = sum / (float)NN;
        float var = sq / (float)NN - mu * mu;
        float sc = g[tid] * rsqrtf(var + 1e-5f);
        snorm[tid] = sc;
        snorm[128 + tid] = bbeta[tid] - mu * sc;
    }
    stageB8(Wt + (3 + layer) * 16384, sB, s, rr);
    __syncthreads();  // snorm ready

#pragma unroll
    for (int it = 0; it < 8; ++it) {
        int lr = it * 16 + rr, gr = r0 + lr;
        union { u16 pk[8]; uint4 v; } uu;
        if (gr < NN) {
            uu.v = *(const uint4*)(h16 + (long)gr * CH + 8 * s);
#pragma unroll
            for (int j = 0; j < 8; ++j) {
                int c = 8 * s + j;
                float v = fmaxf(b2f(uu.pk[j]) * snorm[c] + snorm[128 + c], 0.f);
                uu.pk[j] = f2b(v);
            }
        } else {
#pragma unroll
            for (int j = 0; j < 8; ++j) uu.pk[j] = 0;
        }
        *(uint4*)(&sA[lr * CH + ((s ^ (lr & 15)) * 8)]) = uu.v;
    }
    __syncthreads();
    f32x4 acc[2][8];
    mfma8(sA, sB, acc, wv, quad, l16);
    biasrelu(acc, cb2, l16);
#pragma unroll
    for (int t = 0; t < 8; ++t) {
        int col = t * 16 + l16;
#pragma unroll
        for (int m = 0; m < 2; ++m)
#pragma unroll
            for (int r = 0; r < 4; ++r) {
                int row = r0 + wv * 32 + m * 16 + quad * 4 + r;
                if (row < NN) xc[(long)row * CH + col] = f2b(acc[m][t][r]);
            }
    }

    if constexpr (LAST) {
        // ---- rec1 ----
        __syncthreads();
        restage(acc, sA, wv, quad, l16);
        stageB8(Wt + 6 * 16384, sB, s, rr);
        __syncthreads();
        mfma8(sA, sB, acc, wv, quad, l16);
        biasrelu(acc, rb1, l16);
        // ---- rec2 ----
        __syncthreads();
        restage(acc, sA, wv, quad, l16);
        stageB8(Wt + 7 * 16384, sB, s, rr);
        __syncthreads();
        mfma8(sA, sB, acc, wv, quad, l16);
        biasrelu(acc, rb2, l16);
        // ---- rec3 (N=4, one 16-col tile) ----
        __syncthreads();
        restage(acc, sA, wv, quad, l16);
        {
            int n = rr;  // 16 B-rows
            uint4 u = *(const uint4*)(Wt + 8 * 16384 + n * CH + 8 * s);
            *(uint4*)(&sB[n * CH + ((s ^ (n & 15)) * 8)]) = u;
        }
        __syncthreads();
        f32x4 a4[2];
        a4[0] = (f32x4){0.f, 0.f, 0.f, 0.f};
        a4[1] = (f32x4){0.f, 0.f, 0.f, 0.f};
        const u16* pa0 = sA + (wv * 32 + l16) * CH;
        const u16* pa1 = pa0 + 16 * CH;
#pragma unroll
        for (int kc = 0; kc < 4; ++kc) {
            int off = (((kc << 2) | quad) ^ l16) << 3;
            s16x8 a0 = *(const s16x8*)(pa0 + off);
            s16x8 a1 = *(const s16x8*)(pa1 + off);
            s16x8 bfr = *(const s16x8*)(sB + l16 * CH + off);
            a4[0] = __builtin_amdgcn_mfma_f32_16x16x32_bf16(a0, bfr, a4[0], 0, 0, 0);
            a4[1] = __builtin_amdgcn_mfma_f32_16x16x32_bf16(a1, bfr, a4[1], 0, 0, 0);
        }
        if (l16 < 4) {
            float bv = rb3[l16];
#pragma unroll
            for (int m = 0; m < 2; ++m)
#pragma unroll
                for (int r = 0; r < 4; ++r) {
                    int row = r0 + wv * 32 + m * 16 + quad * 4 + r;
                    if (row < NN) x_rec[(long)row * 4 + l16] = fmaxf(a4[m][r] + bv, 0.f);
                }
        }
    }
}

// ---------------------------------------------------------------------------
// global_add_pool, parallel: 392 blocks x 128 rows; run-length accumulate.
// ---------------------------------------------------------------------------
__global__ __launch_bounds__(256) void k_pool(const u16* __restrict__ x,
                                              const int* __restrict__ batch,
                                              float* __restrict__ pooled) {
    int r0 = blockIdx.x * 128;
    if (r0 >= NN) return;
    int rend = r0 + 128 < NN ? r0 + 128 : NN;
    int c = threadIdx.x & 127;
    int half = threadIdx.x >> 7;
    int r = r0 + half;
    if (r >= rend) return;
    int g = batch[r];
    float s = 0.f;
    for (; r < rend; r += 2) {
        int gg = batch[r];
        if (gg != g) {
            unsafeAtomicAdd(pooled + g * CH + c, s);
            s = 0.f;
            g = gg;
        }
        s += b2f(x[(long)r * CH + c]);
    }
    unsafeAtomicAdd(pooled + g * CH + c, s);
}

// out[b] = relu(pooled[b] @ W1 + b1) @ W2 + b2  ; grid 64 x 128, all f32
__global__ __launch_bounds__(128) void k_mlp(const float* __restrict__ pooled,
                                             const float* __restrict__ W1,
                                             const float* __restrict__ b1,
                                             const float* __restrict__ W2,
                                             const float* __restrict__ b2,
                                             float* __restrict__ out) {
    __shared__ float p[128], t1[128];
    int b = blockIdx.x, t = threadIdx.x;
    p[t] = pooled[b * CH + t];
    __syncthreads();
    float acc = b1[t];
    for (int k = 0; k < 128; ++k) acc += p[k] * W1[k * 128 + t];
    t1[t] = fmaxf(acc, 0.f);
    __syncthreads();
    if (t < 64) {
        float o = b2[t];
        for (int k = 0; k < 128; ++k) o += t1[k] * W2[k * 64 + t];
        out[b * 64 + t] = o;
    }
}

// ---------------------------------------------------------------------------
extern "C" void kernel_launch(void* const* d_in, const int* in_sizes, int n_in,
                              void* d_out, int out_size, void* d_ws, size_t ws_size,
                              hipStream_t stream) {
    const float* x_in   = (const float*)d_in[0];
    const int*   ei     = (const int*)d_in[1];
    const int*   batch  = (const int*)d_in[2];
    const float* convW1 = (const float*)d_in[3];
    const float* convb1 = (const float*)d_in[4];
    const float* bn_g   = (const float*)d_in[5];
    const float* bn_b   = (const float*)d_in[6];
    const float* convW2 = (const float*)d_in[7];
    const float* convb2 = (const float*)d_in[8];
    const float* recW1  = (const float*)d_in[9];
    const float* recb1  = (const float*)d_in[10];
    const float* recW2  = (const float*)d_in[11];
    const float* recb2  = (const float*)d_in[12];
    const float* recW3  = (const float*)d_in[13];
    const float* recb3  = (const float*)d_in[14];
    const float* mlpW1  = (const float*)d_in[15];
    const float* mlpb1  = (const float*)d_in[16];
    const float* mlpW2  = (const float*)d_in[17];
    const float* mlpb2  = (const float*)d_in[18];

    float* out   = (float*)d_out;      // [64*64] out, then [50000*4] x_rec
    float* x_rec = out + 4096;

    char* w = (char*)d_ws;
    u16*   x16    = (u16*)w;    w += (size_t)NN * CH * 2;      // bf16 copy of x_in
    u16*   y16    = (u16*)w;    w += (size_t)NN * CH * 2;      // gather output / h in-place
    u16*   xc     = (u16*)w;    w += (size_t)NN * CH * 2;      // layer output
    u16*   Wt     = (u16*)w;    w += (size_t)9 * 16384 * 2;    // transposed bf16 weights
    float* gstats = (float*)w;  w += (size_t)3 * 256 * 4;      // BN sums per layer
    float* pooled = (float*)w;  w += (size_t)BB * CH * 4;
    int*   deg    = (int*)w;    w += (size_t)NN * 4;
    int*   bsum   = (int*)w;    w += (size_t)NSB * 4;
    int*   rowptr = (int*)w;    w += (size_t)(NN + 1) * 4;
    int*   cur    = (int*)w;    w += (size_t)NN * 4;
    int*   perm   = (int*)w;    w += (size_t)EE * 4;

    dim3 b256(256), b128(128);

    // prep (zero + cvt + transpose) then CSR build
    k_prep<<<3125, b256, 0, stream>>>(x_in, x16, convW1, convW2, recW1, recW2,
                                      recW3, Wt, deg, pooled, gstats);
    k_count<<<2344, b256, 0, stream>>>(ei, deg);
    k_scanA<<<NSB, b256, 0, stream>>>(deg, bsum);
    k_scanB<<<NSB, b256, 0, stream>>>(deg, bsum, rowptr, cur);
    k_fill<<<2344, b256, 0, stream>>>(ei, cur, perm);

    const u16* cur_x = x16;
    for (int l = 0; l < LL; ++l) {
        k_gather<<<3125, b256, 0, stream>>>(cur_x, rowptr, perm, y16);
        k_gemm1<<<NGB, b256, 0, stream>>>(y16, Wt, l, convb1 + l * 128,
                                          gstats + l * 256);
        if (l < LL - 1)
            k_gemm2<false><<<NGB, b256, 0, stream>>>(
                y16, Wt, l, bn_g + l * 128, bn_b + l * 128, gstats + l * 256,
                convb2 + l * 128, xc, recb1, recb2, recb3, x_rec);
        else
            k_gemm2<true><<<NGB, b256, 0, stream>>>(
                y16, Wt, l, bn_g + l * 128, bn_b + l * 128, gstats + l * 256,
                convb2 + l * 128, xc, recb1, recb2, recb3, x_rec);
        cur_x = xc;
    }
    // pooling + final MLP
    k_pool<<<NPB, b256, 0, stream>>>(xc, batch, pooled);
    k_mlp<<<64, b128, 0, stream>>>(pooled, mlpW1, mlpb1, mlpW2, mlpb2, out);
}

// Round 5
// 370.443 us; speedup vs baseline: 1.2854x; 1.0170x over previous
//
#include <hip/hip_runtime.h>

#define NN 50000
#define EE 600000
#define BB 64
#define CH 128
#define LL 3
#define NGB 391   // GEMM/layer row-blocks = ceil(50000/128)
#define NGA 3128  // gather blocks = 4 chunks * ceil(50000/64)
#define NSB 196   // scan blocks = ceil(50000/256)
#define NPB 392   // pool blocks = ceil(50000/128)

typedef unsigned short u16;
typedef unsigned int u32;
typedef short s16x8 __attribute__((ext_vector_type(8)));
typedef float f32x4 __attribute__((ext_vector_type(4)));

// Node features live in CHUNK-MAJOR layout: F[c][n][32], c = col>>5.
// Per-XCD gather working set = 50000*32*2B = 3.2MB < 4MB XCD L2.

__device__ __forceinline__ u16 f2b(float f) {
    u32 x = __float_as_uint(f);
    return (u16)((x + 0x7FFFu + ((x >> 16) & 1u)) >> 16);  // RNE f32->bf16
}
__device__ __forceinline__ float b2f(u16 u) {
    return __uint_as_float(((u32)u) << 16);
}

// ---------------------------------------------------------------------------
// k_prep: fused zero (deg/pooled/gstats) + x->bf16 cvt (chunk-major) +
// weight transpose. grid 3125 x 256.
// slots 0-2: convW1[l], 3-5: convW2[l], 6: recW1, 7: recW2, 8: recW3 (zero-pad)
// ---------------------------------------------------------------------------
__global__ __launch_bounds__(256) void k_prep(
    const float* __restrict__ x, u16* __restrict__ x16,
    const float* __restrict__ cW1, const float* __restrict__ cW2,
    const float* __restrict__ rW1, const float* __restrict__ rW2,
    const float* __restrict__ rW3, u16* __restrict__ Wt,
    int* __restrict__ deg, float* __restrict__ pooled,
    float* __restrict__ gstats) {
    int gid = blockIdx.x * 256 + threadIdx.x;

    // task 1: cvt, row-major f32 -> chunk-major bf16
    long base = (long)gid * 8;
    if (base < (long)NN * CH) {
        float4 f0 = *(const float4*)(x + base);
        float4 f1 = *(const float4*)(x + base + 4);
        union { u16 pk[8]; uint4 v; } uu;
        uu.pk[0] = f2b(f0.x); uu.pk[1] = f2b(f0.y);
        uu.pk[2] = f2b(f0.z); uu.pk[3] = f2b(f0.w);
        uu.pk[4] = f2b(f1.x); uu.pk[5] = f2b(f1.y);
        uu.pk[6] = f2b(f1.z); uu.pk[7] = f2b(f1.w);
        long row = base >> 7;
        int col = (int)(base & 127);
        *(uint4*)(x16 + ((size_t)(col >> 5) * NN + row) * 32 + (col & 31)) = uu.v;
    }
    // task 2: weight transpose
    if (gid < 8 * 16384) {
        int slot = gid >> 14;
        int wi = gid & 16383;
        int k = wi >> 7, n = wi & 127;
        const float* src = slot < 3 ? cW1 + slot * 16384
                         : slot < 6 ? cW2 + (slot - 3) * 16384
                         : slot == 6 ? rW1 : rW2;
        Wt[slot * 16384 + n * 128 + k] = f2b(src[wi]);
    } else if (gid < 9 * 16384) {
        int j = gid - 8 * 16384;
        int n = j >> 7, k = j & 127;
        Wt[8 * 16384 + j] = (n < 4) ? f2b(rW3[k * 4 + n]) : (u16)0;
    }
    // task 3: zeroing
    if (gid < NN) deg[gid] = 0;
    int j2 = gid - NN;
    if (j2 >= 0 && j2 < BB * CH) pooled[j2] = 0.f;
    int k2 = j2 - BB * CH;
    if (k2 >= 0 && k2 < 3 * 256) gstats[k2] = 0.f;
}

__global__ __launch_bounds__(256) void k_count(const int* __restrict__ ei,
                                               int* __restrict__ deg) {
    int e = blockIdx.x * 256 + threadIdx.x;
    if (e < EE) atomicAdd(&deg[ei[EE + e]], 1);
}

// stage A: per-block (256 elems) sum of deg -> bsum[blk]
__global__ __launch_bounds__(256) void k_scanA(const int* __restrict__ deg,
                                               int* __restrict__ bsum) {
    __shared__ int sm[256];
    int i = blockIdx.x * 256 + threadIdx.x;
    sm[threadIdx.x] = (i < NN) ? deg[i] : 0;
    __syncthreads();
    for (int off = 128; off > 0; off >>= 1) {
        if (threadIdx.x < off) sm[threadIdx.x] += sm[threadIdx.x + off];
        __syncthreads();
    }
    if (threadIdx.x == 0) bsum[blockIdx.x] = sm[0];
}

// stage B: scan bsum in LDS -> block offset; local scan -> rowptr & cur
__global__ __launch_bounds__(256) void k_scanB(const int* __restrict__ deg,
                                               const int* __restrict__ bsum,
                                               int* __restrict__ rowptr,
                                               int* __restrict__ cur) {
    __shared__ int sb[256], sd[256];
    int t = threadIdx.x;
    sb[t] = (t < NSB) ? bsum[t] : 0;
    __syncthreads();
    for (int off = 1; off < 256; off <<= 1) {
        int v = (t >= off) ? sb[t - off] : 0;
        __syncthreads();
        sb[t] += v;
        __syncthreads();
    }
    int blockOff = (blockIdx.x == 0) ? 0 : sb[blockIdx.x - 1];
    int i = blockIdx.x * 256 + t;
    int d = (i < NN) ? deg[i] : 0;
    sd[t] = d;
    __syncthreads();
    for (int off = 1; off < 256; off <<= 1) {
        int v = (t >= off) ? sd[t - off] : 0;
        __syncthreads();
        sd[t] += v;
        __syncthreads();
    }
    int excl = blockOff + sd[t] - d;
    if (i < NN) { rowptr[i] = excl; cur[i] = excl; }
    if (i == NN - 1) rowptr[NN] = excl + d;
}

__global__ __launch_bounds__(256) void k_fill(const int* __restrict__ ei,
                                              int* __restrict__ cur,
                                              u16* __restrict__ perm) {
    int e = blockIdx.x * 256 + threadIdx.x;
    if (e < EE) {
        int dst = ei[EE + e];
        int idx = atomicAdd(&cur[dst], 1);
        perm[idx] = (u16)ei[e];
    }
}

// ---------------------------------------------------------------------------
// Gather, XCD-chunk-resident: y[c][dst][*] = bf16( x[c][dst] + sum x[c][src] )
// chunk = blockIdx.x & 3; XCD = bid % 8 -> each XCD touches exactly one chunk
// (3.2MB, L2-resident). One dst per 4-lane group (uint4 = 8 bf16/lane);
// 4-way unrolled edge loop, 4 independent accumulator sets.
// ---------------------------------------------------------------------------
__global__ __launch_bounds__(256) void k_gather(const u16* __restrict__ x,
                                                const int* __restrict__ rowptr,
                                                const u16* __restrict__ perm,
                                                u16* __restrict__ y) {
    int chunk = blockIdx.x & 3;
    int rb = blockIdx.x >> 2;
    int dst = rb * 64 + (threadIdx.x >> 2);
    if (dst >= NN) return;
    int gl = threadIdx.x & 3;
    const u16* xb = x + (size_t)chunk * NN * 32 + gl * 8;
    int beg = rowptr[dst], end = rowptr[dst + 1];
    union { u16 pk[8]; uint4 v; } uu;
    uu.v = *(const uint4*)(xb + (size_t)dst * 32);
    float a[8], b[8], c[8], d[8];
#pragma unroll
    for (int j = 0; j < 8; ++j) { a[j] = b2f(uu.pk[j]); b[j] = 0.f; c[j] = 0.f; d[j] = 0.f; }
    int e = beg;
    for (; e + 3 < end; e += 4) {
        int s0 = perm[e], s1 = perm[e + 1], s2 = perm[e + 2], s3 = perm[e + 3];
        union { u16 pk[8]; uint4 v; } v0, v1, v2, v3;
        v0.v = *(const uint4*)(xb + (size_t)s0 * 32);
        v1.v = *(const uint4*)(xb + (size_t)s1 * 32);
        v2.v = *(const uint4*)(xb + (size_t)s2 * 32);
        v3.v = *(const uint4*)(xb + (size_t)s3 * 32);
#pragma unroll
        for (int j = 0; j < 8; ++j) {
            a[j] += b2f(v0.pk[j]); b[j] += b2f(v1.pk[j]);
            c[j] += b2f(v2.pk[j]); d[j] += b2f(v3.pk[j]);
        }
    }
    for (; e < end; ++e) {
        int s0 = perm[e];
        union { u16 pk[8]; uint4 v; } v0;
        v0.v = *(const uint4*)(xb + (size_t)s0 * 32);
#pragma unroll
        for (int j = 0; j < 8; ++j) a[j] += b2f(v0.pk[j]);
    }
    union { u16 pk[8]; uint4 v; } ov;
#pragma unroll
    for (int j = 0; j < 8; ++j) ov.pk[j] = f2b((a[j] + b[j]) + (c[j] + d[j]));
    *(uint4*)(y + (size_t)chunk * NN * 32 + (size_t)dst * 32 + gl * 8) = ov.v;
}

// ---------------------------------------------------------------------------
// Shared GEMM building blocks (layouts verified m89/m91; XOR-swizzle c^(r&15))
// ---------------------------------------------------------------------------
__device__ __forceinline__ void stageB8(const u16* __restrict__ Wt, u16* sB,
                                        int s, int rr) {
#pragma unroll
    for (int it = 0; it < 8; ++it) {
        int n = it * 16 + rr;
        uint4 u = *(const uint4*)(Wt + n * CH + 8 * s);
        *(uint4*)(&sB[n * CH + ((s ^ (n & 15)) * 8)]) = u;
    }
}

__device__ __forceinline__ void mfma8(const u16* sA, const u16* sB,
                                      f32x4 acc[2][8], int wv, int quad, int l16) {
    f32x4 z = {0.f, 0.f, 0.f, 0.f};
#pragma unroll
    for (int m = 0; m < 2; ++m)
#pragma unroll
        for (int t = 0; t < 8; ++t) acc[m][t] = z;
    const u16* pa0 = sA + (wv * 32 + l16) * CH;
    const u16* pa1 = pa0 + 16 * CH;
#pragma unroll
    for (int kc = 0; kc < 4; ++kc) {
        int off = (((kc << 2) | quad) ^ l16) << 3;
        s16x8 a0 = *(const s16x8*)(pa0 + off);
        s16x8 a1 = *(const s16x8*)(pa1 + off);
#pragma unroll
        for (int t = 0; t < 8; ++t) {
            s16x8 bfr = *(const s16x8*)(sB + (t * 16 + l16) * CH + off);
            acc[0][t] = __builtin_amdgcn_mfma_f32_16x16x32_bf16(a0, bfr, acc[0][t], 0, 0, 0);
            acc[1][t] = __builtin_amdgcn_mfma_f32_16x16x32_bf16(a1, bfr, acc[1][t], 0, 0, 0);
        }
    }
}

__device__ __forceinline__ void biasrelu(f32x4 acc[2][8],
                                         const float* __restrict__ bias, int l16) {
#pragma unroll
    for (int t = 0; t < 8; ++t) {
        float bv = bias[t * 16 + l16];
#pragma unroll
        for (int m = 0; m < 2; ++m)
#pragma unroll
            for (int r = 0; r < 4; ++r)
                acc[m][t][r] = fmaxf(acc[m][t][r] + bv, 0.f);
    }
}

// write C tile (in acc) back into sA as bf16 with the A-read XOR-swizzle.
__device__ __forceinline__ void restage(const f32x4 acc[2][8], u16* sA,
                                        int wv, int quad, int l16) {
#pragma unroll
    for (int t = 0; t < 8; ++t) {
        int chunk = (t << 1) | (l16 >> 3);
        int o7 = l16 & 7;
#pragma unroll
        for (int m = 0; m < 2; ++m)
#pragma unroll
            for (int r = 0; r < 4; ++r) {
                int lr = wv * 32 + m * 16 + quad * 4 + r;
                sA[lr * CH + ((chunk ^ (lr & 15)) << 3) + o7] = f2b(acc[m][t][r]);
            }
    }
}

// ---------------------------------------------------------------------------
// k_gemm1: h = y@W1 + b1 ; block stat partials -> atomicAdd gstats ;
// reads y16 chunk-major, writes h16 row-major (pre-BN bf16).
// 128 rows/block, 2 blocks/CU.
// ---------------------------------------------------------------------------
__global__ __launch_bounds__(256, 2) void k_gemm1(
    const u16* __restrict__ y16, const u16* __restrict__ Wt, int layer,
    const float* __restrict__ cb1, float* __restrict__ gstats,
    u16* __restrict__ h16) {
    __shared__ u16 sA[128 * CH];
    __shared__ u16 sB[128 * CH];
    const int tid = threadIdx.x;
    const int s = tid & 15, rr = tid >> 4;
    const int r0 = blockIdx.x * 128;
    const int lane = tid & 63, wv = tid >> 6, quad = lane >> 4, l16 = lane & 15;

    stageB8(Wt + layer * 16384, sB, s, rr);
#pragma unroll
    for (int it = 0; it < 8; ++it) {
        int lr = it * 16 + rr, gr = r0 + lr;
        union { u16 pk[8]; uint4 v; } uu;
        if (gr < NN) {
            // chunk-major read: chunk = s>>2, within-chunk col = (s&3)*8
            uu.v = *(const uint4*)(y16 + ((size_t)(s >> 2) * NN + gr) * 32 + (s & 3) * 8);
        } else {
#pragma unroll
            for (int j = 0; j < 8; ++j) uu.pk[j] = 0;
        }
        *(uint4*)(&sA[lr * CH + ((s ^ (lr & 15)) * 8)]) = uu.v;
    }
    __syncthreads();
    f32x4 acc[2][8];
    mfma8(sA, sB, acc, wv, quad, l16);

    // bias add (h pre-relu kept in acc) + stats over valid rows
    float ss[8], qq[8];
#pragma unroll
    for (int t = 0; t < 8; ++t) {
        float bv = cb1[t * 16 + l16];
        ss[t] = 0.f; qq[t] = 0.f;
#pragma unroll
        for (int m = 0; m < 2; ++m) {
            int rbase = r0 + wv * 32 + m * 16 + quad * 4;
#pragma unroll
            for (int r = 0; r < 4; ++r) {
                float v = acc[m][t][r] + bv;
                acc[m][t][r] = v;
                if (rbase + r < NN) { ss[t] += v; qq[t] += v * v; }
            }
        }
    }
#pragma unroll
    for (int t = 0; t < 8; ++t) {
        ss[t] += __shfl_xor(ss[t], 16);
        ss[t] += __shfl_xor(ss[t], 32);
        qq[t] += __shfl_xor(qq[t], 16);
        qq[t] += __shfl_xor(qq[t], 32);
    }
    float* red = (float*)sA;
    __syncthreads();  // all waves done reading sA in mfma8
    if (lane < 16) {
#pragma unroll
        for (int t = 0; t < 8; ++t) {
            red[wv * 256 + t * 16 + l16] = ss[t];
            red[wv * 256 + 128 + t * 16 + l16] = qq[t];
        }
    }
    __syncthreads();
    unsafeAtomicAdd(&gstats[tid],
                    red[tid] + red[256 + tid] + red[512 + tid] + red[768 + tid]);

    // write h (pre-BN, bf16), row-major
#pragma unroll
    for (int t = 0; t < 8; ++t) {
        int col = t * 16 + l16;
#pragma unroll
        for (int m = 0; m < 2; ++m)
#pragma unroll
            for (int r = 0; r < 4; ++r) {
                int row = r0 + wv * 32 + m * 16 + quad * 4 + r;
                if (row < NN) h16[(long)row * CH + col] = f2b(acc[m][t][r]);
            }
    }
}

// ---------------------------------------------------------------------------
// k_gemm2: sc/sh from gstats (plain loads — kernel-boundary coherence);
// BN+ReLU folded into the A-stage bf16 conversion; GEMM2 -> xc (chunk-major).
// LAST: tile-resident rec1/rec2/rec3 -> x_rec.
// ---------------------------------------------------------------------------
template <bool LAST>
__global__ __launch_bounds__(256, 2) void k_gemm2(
    const u16* __restrict__ h16, const u16* __restrict__ Wt, int layer,
    const float* __restrict__ g, const float* __restrict__ bbeta,
    const float* __restrict__ gstats, const float* __restrict__ cb2,
    u16* __restrict__ xc,
    const float* __restrict__ rb1, const float* __restrict__ rb2,
    const float* __restrict__ rb3, float* __restrict__ x_rec) {
    __shared__ u16 sA[128 * CH];
    __shared__ u16 sB[128 * CH];
    __shared__ float snorm[256];  // sc[128], sh[128]
    const int tid = threadIdx.x;
    const int s = tid & 15, rr = tid >> 4;
    const int r0 = blockIdx.x * 128;
    const int lane = tid & 63, wv = tid >> 6, quad = lane >> 4, l16 = lane & 15;

    if (tid < 128) {
        float sum = gstats[tid];
        float sq = gstats[128 + tid];
        float mu = sum / (float)NN;
        float var = sq / (float)NN - mu * mu;
        float sc = g[tid] * rsqrtf(var + 1e-5f);
        snorm[tid] = sc;
        snorm[128 + tid] = bbeta[tid] - mu * sc;
    }
    stageB8(Wt + (3 + layer) * 16384, sB, s, rr);
    __syncthreads();  // snorm ready

#pragma unroll
    for (int it = 0; it < 8; ++it) {
        int lr = it * 16 + rr, gr = r0 + lr;
        union { u16 pk[8]; uint4 v; } uu;
        if (gr < NN) {
            uu.v = *(const uint4*)(h16 + (long)gr * CH + 8 * s);
#pragma unroll
            for (int j = 0; j < 8; ++j) {
                int c = 8 * s + j;
                float v = fmaxf(b2f(uu.pk[j]) * snorm[c] + snorm[128 + c], 0.f);
                uu.pk[j] = f2b(v);
            }
        } else {
#pragma unroll
            for (int j = 0; j < 8; ++j) uu.pk[j] = 0;
        }
        *(uint4*)(&sA[lr * CH + ((s ^ (lr & 15)) * 8)]) = uu.v;
    }
    __syncthreads();
    f32x4 acc[2][8];
    mfma8(sA, sB, acc, wv, quad, l16);
    biasrelu(acc, cb2, l16);
    // write xc chunk-major: col = t*16+l16 -> chunk t>>1, within (t&1)*16+l16
#pragma unroll
    for (int t = 0; t < 8; ++t) {
        u16* xcp = xc + (size_t)(t >> 1) * NN * 32 + (t & 1) * 16 + l16;
#pragma unroll
        for (int m = 0; m < 2; ++m)
#pragma unroll
            for (int r = 0; r < 4; ++r) {
                int row = r0 + wv * 32 + m * 16 + quad * 4 + r;
                if (row < NN) xcp[(size_t)row * 32] = f2b(acc[m][t][r]);
            }
    }

    if constexpr (LAST) {
        // ---- rec1 ----
        __syncthreads();
        restage(acc, sA, wv, quad, l16);
        stageB8(Wt + 6 * 16384, sB, s, rr);
        __syncthreads();
        mfma8(sA, sB, acc, wv, quad, l16);
        biasrelu(acc, rb1, l16);
        // ---- rec2 ----
        __syncthreads();
        restage(acc, sA, wv, quad, l16);
        stageB8(Wt + 7 * 16384, sB, s, rr);
        __syncthreads();
        mfma8(sA, sB, acc, wv, quad, l16);
        biasrelu(acc, rb2, l16);
        // ---- rec3 (N=4, one 16-col tile) ----
        __syncthreads();
        restage(acc, sA, wv, quad, l16);
        {
            int n = rr;  // 16 B-rows
            uint4 u = *(const uint4*)(Wt + 8 * 16384 + n * CH + 8 * s);
            *(uint4*)(&sB[n * CH + ((s ^ (n & 15)) * 8)]) = u;
        }
        __syncthreads();
        f32x4 a4[2];
        a4[0] = (f32x4){0.f, 0.f, 0.f, 0.f};
        a4[1] = (f32x4){0.f, 0.f, 0.f, 0.f};
        const u16* pa0 = sA + (wv * 32 + l16) * CH;
        const u16* pa1 = pa0 + 16 * CH;
#pragma unroll
        for (int kc = 0; kc < 4; ++kc) {
            int off = (((kc << 2) | quad) ^ l16) << 3;
            s16x8 a0 = *(const s16x8*)(pa0 + off);
            s16x8 a1 = *(const s16x8*)(pa1 + off);
            s16x8 bfr = *(const s16x8*)(sB + l16 * CH + off);
            a4[0] = __builtin_amdgcn_mfma_f32_16x16x32_bf16(a0, bfr, a4[0], 0, 0, 0);
            a4[1] = __builtin_amdgcn_mfma_f32_16x16x32_bf16(a1, bfr, a4[1], 0, 0, 0);
        }
        if (l16 < 4) {
            float bv = rb3[l16];
#pragma unroll
            for (int m = 0; m < 2; ++m)
#pragma unroll
                for (int r = 0; r < 4; ++r) {
                    int row = r0 + wv * 32 + m * 16 + quad * 4 + r;
                    if (row < NN) x_rec[(long)row * 4 + l16] = fmaxf(a4[m][r] + bv, 0.f);
                }
        }
    }
}

// ---------------------------------------------------------------------------
// global_add_pool, parallel: 392 blocks x 128 rows; run-length accumulate.
// Reads xc chunk-major.
// ---------------------------------------------------------------------------
__global__ __launch_bounds__(256) void k_pool(const u16* __restrict__ x,
                                              const int* __restrict__ batch,
                                              float* __restrict__ pooled) {
    int r0 = blockIdx.x * 128;
    if (r0 >= NN) return;
    int rend = r0 + 128 < NN ? r0 + 128 : NN;
    int c = threadIdx.x & 127;
    int half = threadIdx.x >> 7;
    int r = r0 + half;
    if (r >= rend) return;
    const u16* xp = x + (size_t)(c >> 5) * NN * 32 + (c & 31);
    int g = batch[r];
    float s = 0.f;
    for (; r < rend; r += 2) {
        int gg = batch[r];
        if (gg != g) {
            unsafeAtomicAdd(pooled + g * CH + c, s);
            s = 0.f;
            g = gg;
        }
        s += b2f(xp[(size_t)r * 32]);
    }
    unsafeAtomicAdd(pooled + g * CH + c, s);
}

// out[b] = relu(pooled[b] @ W1 + b1) @ W2 + b2  ; grid 64 x 128, all f32
__global__ __launch_bounds__(128) void k_mlp(const float* __restrict__ pooled,
                                             const float* __restrict__ W1,
                                             const float* __restrict__ b1,
                                             const float* __restrict__ W2,
                                             const float* __restrict__ b2,
                                             float* __restrict__ out) {
    __shared__ float p[128], t1[128];
    int b = blockIdx.x, t = threadIdx.x;
    p[t] = pooled[b * CH + t];
    __syncthreads();
    float acc = b1[t];
    for (int k = 0; k < 128; ++k) acc += p[k] * W1[k * 128 + t];
    t1[t] = fmaxf(acc, 0.f);
    __syncthreads();
    if (t < 64) {
        float o = b2[t];
        for (int k = 0; k < 128; ++k) o += t1[k] * W2[k * 64 + t];
        out[b * 64 + t] = o;
    }
}

// ---------------------------------------------------------------------------
extern "C" void kernel_launch(void* const* d_in, const int* in_sizes, int n_in,
                              void* d_out, int out_size, void* d_ws, size_t ws_size,
                              hipStream_t stream) {
    const float* x_in   = (const float*)d_in[0];
    const int*   ei     = (const int*)d_in[1];
    const int*   batch  = (const int*)d_in[2];
    const float* convW1 = (const float*)d_in[3];
    const float* convb1 = (const float*)d_in[4];
    const float* bn_g   = (const float*)d_in[5];
    const float* bn_b   = (const float*)d_in[6];
    const float* convW2 = (const float*)d_in[7];
    const float* convb2 = (const float*)d_in[8];
    const float* recW1  = (const float*)d_in[9];
    const float* recb1  = (const float*)d_in[10];
    const float* recW2  = (const float*)d_in[11];
    const float* recb2  = (const float*)d_in[12];
    const float* recW3  = (const float*)d_in[13];
    const float* recb3  = (const float*)d_in[14];
    const float* mlpW1  = (const float*)d_in[15];
    const float* mlpb1  = (const float*)d_in[16];
    const float* mlpW2  = (const float*)d_in[17];
    const float* mlpb2  = (const float*)d_in[18];

    float* out   = (float*)d_out;      // [64*64] out, then [50000*4] x_rec
    float* x_rec = out + 4096;

    char* w = (char*)d_ws;
    u16*   x16    = (u16*)w;    w += (size_t)NN * CH * 2;      // bf16 x, chunk-major
    u16*   y16    = (u16*)w;    w += (size_t)NN * CH * 2;      // gather out, chunk-major
    u16*   h16    = (u16*)w;    w += (size_t)NN * CH * 2;      // GEMM1 out, row-major
    u16*   xc     = (u16*)w;    w += (size_t)NN * CH * 2;      // layer out, chunk-major
    u16*   Wt     = (u16*)w;    w += (size_t)9 * 16384 * 2;    // transposed bf16 weights
    float* gstats = (float*)w;  w += (size_t)3 * 256 * 4;      // BN sums per layer
    float* pooled = (float*)w;  w += (size_t)BB * CH * 4;
    int*   deg    = (int*)w;    w += (size_t)NN * 4;
    int*   bsum   = (int*)w;    w += (size_t)NSB * 4;
    int*   rowptr = (int*)w;    w += (size_t)(NN + 1) * 4;
    int*   cur    = (int*)w;    w += (size_t)NN * 4;
    u16*   perm   = (u16*)w;    w += (size_t)EE * 2;

    dim3 b256(256), b128(128);

    // prep (zero + cvt + transpose) then CSR build
    k_prep<<<3125, b256, 0, stream>>>(x_in, x16, convW1, convW2, recW1, recW2,
                                      recW3, Wt, deg, pooled, gstats);
    k_count<<<2344, b256, 0, stream>>>(ei, deg);
    k_scanA<<<NSB, b256, 0, stream>>>(deg, bsum);
    k_scanB<<<NSB, b256, 0, stream>>>(deg, bsum, rowptr, cur);
    k_fill<<<2344, b256, 0, stream>>>(ei, cur, perm);

    const u16* cur_x = x16;
    for (int l = 0; l < LL; ++l) {
        k_gather<<<NGA, b256, 0, stream>>>(cur_x, rowptr, perm, y16);
        k_gemm1<<<NGB, b256, 0, stream>>>(y16, Wt, l, convb1 + l * 128,
                                          gstats + l * 256, h16);
        if (l < LL - 1)
            k_gemm2<false><<<NGB, b256, 0, stream>>>(
                h16, Wt, l, bn_g + l * 128, bn_b + l * 128, gstats + l * 256,
                convb2 + l * 128, xc, recb1, recb2, recb3, x_rec);
        else
            k_gemm2<true><<<NGB, b256, 0, stream>>>(
                h16, Wt, l, bn_g + l * 128, bn_b + l * 128, gstats + l * 256,
                convb2 + l * 128, xc, recb1, recb2, recb3, x_rec);
        cur_x = xc;
    }
    // pooling + final MLP
    k_pool<<<NPB, b256, 0, stream>>>(xc, batch, pooled);
    k_mlp<<<64, b128, 0, stream>>>(pooled, mlpW1, mlpb1, mlpW2, mlpb2, out);
}